// Round 5
// baseline (410.205 us; speedup 1.0000x reference)
//
#include <hip/hip_runtime.h>

// VectorQuantizer on MI355X (gfx950). Round 5: d_out is FLOAT32 (not bf16).
// d_out (f32 elements): [z_q 33554432][idx 131072][loss 1]  (out_size 33685505)
// Scratch inside z_q's 134MB byte region (overwritten by K3 at the end):
//   bytes [67108864, 67633152)  swizzled bf16 codebook image (1024x256, 512KB)
//   bytes [68157440, 69206016)  cand4: u64[131072] packed top-4 codes (1MB)
// Loss slot (out[33685504]) doubles as the f32 accumulator: K0 zeroes it,
// K2 atomicAdds partial sums, K4 rescales in place. d_ws unused.

typedef __attribute__((ext_vector_type(8))) short short8;
typedef __attribute__((ext_vector_type(4))) float f32x4;
typedef __attribute__((ext_vector_type(4))) unsigned int u32x4;
typedef unsigned long long u64;

#define ZQ_N     33554432u
#define IDX_OFF  33554432u
#define LOSS_OFF 33685504u
#define IMG_BYTE  67108864u
#define CAND_BYTE 68157440u

__device__ __forceinline__ unsigned short f2bf(float f) {
  unsigned u = __float_as_uint(f);
  unsigned r = (u + 0x7FFFu + ((u >> 16) & 1u)) >> 16;  // RNE
  return (unsigned short)r;
}

// numpy pairwise combine of 8 accumulators
#define COMB(r) __fadd_rn(__fadd_rn(__fadd_rn(r[0], r[1]), __fadd_rn(r[2], r[3])), \
                          __fadd_rn(__fadd_rn(r[4], r[5]), __fadd_rn(r[6], r[7])))

// ---------------- K0: swizzled bf16 codebook image + zero loss slot -----------
extern "C" __global__ __launch_bounds__(256) void vq_r5_k0(const float* __restrict__ cb,
                                                           unsigned char* __restrict__ img,
                                                           float* __restrict__ outf) {
  unsigned tid = blockIdx.x * 256u + threadIdx.x;  // 131072 = (code, dpair)
  unsigned code = tid >> 7, dp = tid & 127u;
  const float* p = cb + (size_t)code * 256u + dp * 2u;
  float x0 = p[0], x1 = p[1];
  unsigned u = ((unsigned)f2bf(x1) << 16) | (unsigned)f2bf(x0);
  unsigned byte = code * 512u + ((dp * 4u) ^ ((code & 7u) << 4));
  *(unsigned*)(img + byte) = u;
  if (tid == 0) outf[LOSS_OFF] = 0.0f;
}

// ---------------- K1: bf16 MFMA GEMM -> per-point top-4 candidate codes -------
// 256 thr (4 waves = 2M x 2N), tile 64 pts x 32 codes/chunk, D=256, 32 chunks.
extern "C" __global__ __launch_bounds__(256) void vq_r5_k1(const float* __restrict__ x,
                                                           const unsigned char* __restrict__ img,
                                                           u64* __restrict__ cand4) {
  __shared__ __attribute__((aligned(16))) char Ab[32768];  // [64 pt][256 d] bf16, swizzled
  __shared__ __attribute__((aligned(16))) char Bb[16384];  // [32 code][256 d] bf16, swizzled
  __shared__ float kk[2048];                               // [64 pt][16 cls][2] keys
  const int t = threadIdx.x;
  const int bid = blockIdx.x;  // 2048 blocks, 64 points each
  const int lane = t & 63;
  const int w = t >> 6;
  const int wm = w >> 1, wn = w & 1;
  const int g = lane >> 4, c16 = lane & 15;

  {  // stage A: x[b, d, hw] -> Ab[pt][d] bf16 (swizzled rows)
    const size_t xbase = (size_t)(bid >> 6) * 1048576u + (size_t)(bid & 63) * 64u;
    for (int i = 0; i < 32; ++i) {
      int P = i * 256 + t;
      int ptl = P & 63, dp = P >> 6;
      float x0 = x[xbase + (size_t)(2 * dp) * 4096u + (unsigned)ptl];
      float x1 = x[xbase + (size_t)(2 * dp + 1) * 4096u + (unsigned)ptl];
      unsigned u = ((unsigned)f2bf(x1) << 16) | (unsigned)f2bf(x0);
      int byte = ptl * 512 + ((dp * 4) ^ ((ptl & 7) << 4));
      *(unsigned*)(Ab + byte) = u;
    }
  }

  float t1[8], t2[8];
#pragma unroll
  for (int s = 0; s < 8; ++s) { t1[s] = -__builtin_inff(); t2[s] = -__builtin_inff(); }

  for (int kc = 0; kc < 32; ++kc) {
    __syncthreads();
    {  // stage B chunk (pre-swizzled): 16 KiB flat copy
      const unsigned char* src = img + (size_t)kc * 16384u;
#pragma unroll
      for (int i = 0; i < 4; ++i) {
        int off = (i * 256 + t) * 16;
        *(u32x4*)(Bb + off) = *(const u32x4*)(src + off);
      }
    }
    __syncthreads();

    f32x4 acc0 = (f32x4){0.f, 0.f, 0.f, 0.f};
    f32x4 acc1 = (f32x4){0.f, 0.f, 0.f, 0.f};
#pragma unroll
    for (int ks = 0; ks < 8; ++ks) {
      const int colbyte = (ks * 64 + g * 16) ^ ((lane & 7) << 4);
      short8 a0 = *(const short8*)(Ab + (wm * 32 + c16) * 512 + colbyte);
      short8 a1 = *(const short8*)(Ab + (wm * 32 + 16 + c16) * 512 + colbyte);
      short8 b0 = *(const short8*)(Bb + (wn * 16 + c16) * 512 + colbyte);
      acc0 = __builtin_amdgcn_mfma_f32_16x16x32_bf16(a0, b0, acc0, 0, 0, 0);
      acc1 = __builtin_amdgcn_mfma_f32_16x16x32_bf16(a1, b0, acc1, 0, 0, 0);
    }

    const unsigned codebits = (unsigned)(kc * 32 + wn * 16 + c16);
#pragma unroll
    for (int m = 0; m < 2; ++m)
#pragma unroll
      for (int i = 0; i < 4; ++i) {
        float v = (m == 0) ? acc0[i] : acc1[i];
        float kf = __uint_as_float((__float_as_uint(v) & 0xFFFFFC00u) | codebits);
        int s = m * 4 + i;
        float lo = fminf(t1[s], kf);
        t1[s] = fmaxf(t1[s], kf);
        t2[s] = fmaxf(t2[s], lo);
      }
  }

  // merge lane pairs (c16, c16^8): 64 codes per (wn, c16&7) class
#pragma unroll
  for (int s = 0; s < 8; ++s) {
    float o1 = __shfl_xor(t1[s], 8);
    float o2 = __shfl_xor(t2[s], 8);
    float n1 = fmaxf(t1[s], o1);
    float n2 = fmaxf(fminf(t1[s], o1), fmaxf(t2[s], o2));
    t1[s] = n1; t2[s] = n2;
  }
  if (c16 < 8) {
    const int cls = wn * 8 + c16;
#pragma unroll
    for (int m = 0; m < 2; ++m)
#pragma unroll
      for (int i = 0; i < 4; ++i) {
        int s = m * 4 + i;
        int ptl = wm * 32 + m * 16 + g * 4 + i;
        kk[ptl * 32 + cls * 2] = t1[s];
        kk[ptl * 32 + cls * 2 + 1] = t2[s];
      }
  }
  __syncthreads();

  if (t < 64) {  // per point: top-4 of 32 keys -> packed codes
    float f1 = -__builtin_inff(), f2v = f1, f3 = f1, f4 = f1;
#pragma unroll
    for (int j = 0; j < 32; ++j) {
      float v = kk[t * 32 + ((j + t) & 31)];
      float b1 = fminf(f1, v);   f1 = fmaxf(f1, v);
      float b2 = fminf(f2v, b1); f2v = fmaxf(f2v, b1);
      float b3 = fminf(f3, b2);  f3 = fmaxf(f3, b2);
      f4 = fmaxf(f4, b3);
    }
    u64 pk = (u64)(__float_as_uint(f1) & 1023u)
           | ((u64)(__float_as_uint(f2v) & 1023u) << 16)
           | ((u64)(__float_as_uint(f3) & 1023u) << 32)
           | ((u64)(__float_as_uint(f4) & 1023u) << 48);
    cand4[(size_t)bid * 64u + (unsigned)t] = pk;
  }
}

// ---------------- K2: exact np-f32 rescore -> f32 idx + loss partials ---------
extern "C" __global__ __launch_bounds__(256) void vq_r5_k2(const float* __restrict__ x,
                                                           const float* __restrict__ cb,
                                                           const u64* __restrict__ cand4,
                                                           float* __restrict__ outf) {
#pragma clang fp contract(off)
  __shared__ float red[4];
  const int t = threadIdx.x;
  const unsigned p = blockIdx.x * 256u + (unsigned)t;

  const u64 pk = cand4[p];
  const int c0 = (int)(pk & 1023u);
  const int c1 = (int)((pk >> 16) & 1023u);
  const int c2 = (int)((pk >> 32) & 1023u);
  const int c3 = (int)((pk >> 48) & 1023u);

  const size_t xoff = ((size_t)(p >> 12)) * 1048576u + (size_t)(p & 4095u);
  const float* e0 = cb + (size_t)c0 * 256u;
  const float* e1 = cb + (size_t)c1 * 256u;
  const float* e2 = cb + (size_t)c2 * 256u;
  const float* e3 = cb + (size_t)c3 * 256u;

  double dt0 = 0.0, dt1 = 0.0, dt2 = 0.0, dt3 = 0.0;
  float hs1[2], h0[2], h1[2], h2[2], h3[2];
#pragma unroll
  for (int half = 0; half < 2; ++half) {
    float r[8], a0[8], a1[8], a2[8], a3[8];
#pragma unroll
    for (int j = 0; j < 8; ++j) {  // numpy pairwise: accumulators seeded with a[0..7]
      const int d = half * 128 + j;
      const float xv = x[xoff + (size_t)d * 4096u];
      const float v0 = e0[d], v1 = e1[d], v2 = e2[d], v3 = e3[d];
      r[j]  = __fmul_rn(xv, xv);
      a0[j] = __fmul_rn(v0, v0);
      a1[j] = __fmul_rn(v1, v1);
      a2[j] = __fmul_rn(v2, v2);
      a3[j] = __fmul_rn(v3, v3);
      dt0 = fma((double)xv, (double)v0, dt0);
      dt1 = fma((double)xv, (double)v1, dt1);
      dt2 = fma((double)xv, (double)v2, dt2);
      dt3 = fma((double)xv, (double)v3, dt3);
    }
    for (int i = 8; i < 128; i += 8) {
#pragma unroll
      for (int j = 0; j < 8; ++j) {
        const int d = half * 128 + i + j;
        const float xv = x[xoff + (size_t)d * 4096u];
        const float v0 = e0[d], v1 = e1[d], v2 = e2[d], v3 = e3[d];
        r[j]  = __fadd_rn(r[j],  __fmul_rn(xv, xv));
        a0[j] = __fadd_rn(a0[j], __fmul_rn(v0, v0));
        a1[j] = __fadd_rn(a1[j], __fmul_rn(v1, v1));
        a2[j] = __fadd_rn(a2[j], __fmul_rn(v2, v2));
        a3[j] = __fadd_rn(a3[j], __fmul_rn(v3, v3));
        dt0 = fma((double)xv, (double)v0, dt0);
        dt1 = fma((double)xv, (double)v1, dt1);
        dt2 = fma((double)xv, (double)v2, dt2);
        dt3 = fma((double)xv, (double)v3, dt3);
      }
    }
    hs1[half] = COMB(r);
    h0[half] = COMB(a0); h1[half] = COMB(a1); h2[half] = COMB(a2); h3[half] = COMB(a3);
  }
  const float s1v = __fadd_rn(hs1[0], hs1[1]);
  const float s20 = __fadd_rn(h0[0], h0[1]);
  const float s21 = __fadd_rn(h1[0], h1[1]);
  const float s22 = __fadd_rn(h2[0], h2[1]);
  const float s23 = __fadd_rn(h3[0], h3[1]);

  float bestd = __builtin_inff();
  int besti = 0x7FFFFFFF;
  { float dd = __fsub_rn(__fadd_rn(s1v, s20), __fmul_rn(2.0f, (float)dt0));
    if (dd < bestd || (dd == bestd && c0 < besti)) { bestd = dd; besti = c0; } }
  { float dd = __fsub_rn(__fadd_rn(s1v, s21), __fmul_rn(2.0f, (float)dt1));
    if (dd < bestd || (dd == bestd && c1 < besti)) { bestd = dd; besti = c1; } }
  { float dd = __fsub_rn(__fadd_rn(s1v, s22), __fmul_rn(2.0f, (float)dt2));
    if (dd < bestd || (dd == bestd && c2 < besti)) { bestd = dd; besti = c2; } }
  { float dd = __fsub_rn(__fadd_rn(s1v, s23), __fmul_rn(2.0f, (float)dt3));
    if (dd < bestd || (dd == bestd && c3 < besti)) { bestd = dd; besti = c3; } }

  outf[IDX_OFF + p] = (float)besti;  // f32 idx output (exact integer)

  float sum = bestd;  // loss partial: sum_c (x-q)^2 == s1 + s2 - 2*dot = bestd
#pragma unroll
  for (int off = 32; off > 0; off >>= 1) sum += __shfl_down(sum, off);
  if ((t & 63) == 0) red[t >> 6] = sum;
  __syncthreads();
  if (t == 0) atomicAdd(outf + LOSS_OFF, red[0] + red[1] + red[2] + red[3]);
}

// ---------------- K4: finalize loss in place -----------------------------------
extern "C" __global__ void vq_r5_k4(float* __restrict__ outf) {
  if (threadIdx.x == 0 && blockIdx.x == 0)
    outf[LOSS_OFF] = 2.0f * (outf[LOSS_OFF] / 33554432.0f);
}

// ---------------- K3: z_q straight-through output (f32) ------------------------
extern "C" __global__ __launch_bounds__(256) void vq_r5_k3(const float* __restrict__ x,
                                                           const float* __restrict__ cb,
                                                           float* __restrict__ outf) {
  size_t tid = (size_t)blockIdx.x * 256u + threadIdx.x;  // 8388608 threads x 4 elems
  size_t e = tid * 4u;                                   // covers [0, 33554432)
  unsigned c = (unsigned)((e >> 12) & 255u);
  unsigned b = (unsigned)(e >> 20);
  unsigned hw = (unsigned)(e & 4095u);
  unsigned p = (b << 12) | hw;
  const float* idxf = outf + IDX_OFF;
  int i0 = ((int)idxf[p]) & 1023;
  int i1 = ((int)idxf[p + 1]) & 1023;
  int i2 = ((int)idxf[p + 2]) & 1023;
  int i3 = ((int)idxf[p + 3]) & 1023;
  const float4 xv = *(const float4*)(x + e);
  float q0 = cb[(size_t)i0 * 256u + c];
  float q1 = cb[(size_t)i1 * 256u + c];
  float q2 = cb[(size_t)i2 * 256u + c];
  float q3 = cb[(size_t)i3 * 256u + c];
  // z_q_st = fl(z_e + fl(z_q - z_e)), exact reference op order
  float4 o;
  o.x = __fadd_rn(xv.x, __fsub_rn(q0, xv.x));
  o.y = __fadd_rn(xv.y, __fsub_rn(q1, xv.y));
  o.z = __fadd_rn(xv.z, __fsub_rn(q2, xv.z));
  o.w = __fadd_rn(xv.w, __fsub_rn(q3, xv.w));
  *(float4*)(outf + e) = o;
}

// ---------------- host ---------------------------------------------------------
extern "C" void kernel_launch(void* const* d_in, const int* in_sizes, int n_in,
                              void* d_out, int out_size, void* d_ws, size_t ws_size,
                              hipStream_t stream) {
  const float* x = (const float*)d_in[0];   // [32,256,64,64] f32
  const float* cb = (const float*)d_in[1];  // [1024,256] f32
  float* outf = (float*)d_out;              // f32 outputs
  unsigned char* img = (unsigned char*)d_out + IMG_BYTE;   // scratch in z_q region
  u64* cand4 = (u64*)((unsigned char*)d_out + CAND_BYTE);  // scratch in z_q region
  (void)in_sizes; (void)n_in; (void)out_size; (void)d_ws; (void)ws_size;

  vq_r5_k0<<<512, 256, 0, stream>>>(cb, img, outf);
  vq_r5_k1<<<2048, 256, 0, stream>>>(x, img, cand4);
  vq_r5_k2<<<512, 256, 0, stream>>>(x, cb, cand4, outf);
  vq_r5_k4<<<1, 64, 0, stream>>>(outf);
  vq_r5_k3<<<32768, 256, 0, stream>>>(x, cb, outf);
}

// Round 6
// 315.419 us; speedup vs baseline: 1.3005x; 1.3005x over previous
//
#include <hip/hip_runtime.h>

// VectorQuantizer on MI355X (gfx950). Round 6: K1 restructured (A-in-regs,
// double-buffered B, 1 barrier/chunk), K3 write-only.
// d_out (f32): [z_q 33554432][idx 131072][loss 1]  (out_size 33685505)
// Scratch inside z_q's byte region (overwritten by K3 at the end):
//   bytes [67108864, 67633152)  swizzled bf16 codebook image (1024 x 256, 512KB)
//   bytes [68157440, 69206016)  cand4: u64[131072] packed top-4 codes (1MB)
// Loss slot outf[33685504] = accumulator (K0 zeroes, K2 adds, K4 rescales).

typedef __attribute__((ext_vector_type(8))) short short8;
typedef __attribute__((ext_vector_type(4))) float f32x4;
typedef __attribute__((ext_vector_type(4))) unsigned int u32x4;
typedef unsigned long long u64;

#define IDX_OFF   33554432u
#define LOSS_OFF  33685504u
#define IMG_BYTE  67108864u
#define CAND_BYTE 68157440u

__device__ __forceinline__ unsigned short f2bf(float f) {
  unsigned u = __float_as_uint(f);
  unsigned r = (u + 0x7FFFu + ((u >> 16) & 1u)) >> 16;  // RNE
  return (unsigned short)r;
}

// numpy pairwise combine of 8 accumulators
#define COMB(r) __fadd_rn(__fadd_rn(__fadd_rn(r[0], r[1]), __fadd_rn(r[2], r[3])), \
                          __fadd_rn(__fadd_rn(r[4], r[5]), __fadd_rn(r[6], r[7])))

// ---------------- K0: swizzled bf16 codebook image + zero loss slot -----------
extern "C" __global__ __launch_bounds__(256) void vq_r6_k0(const float* __restrict__ cb,
                                                           unsigned char* __restrict__ img,
                                                           float* __restrict__ outf) {
  unsigned tid = blockIdx.x * 256u + threadIdx.x;  // 131072 = (code, dpair)
  unsigned code = tid >> 7, dp = tid & 127u;
  const float* p = cb + (size_t)code * 256u + dp * 2u;
  float x0 = p[0], x1 = p[1];
  unsigned u = ((unsigned)f2bf(x1) << 16) | (unsigned)f2bf(x0);
  unsigned byte = code * 512u + ((dp * 4u) ^ ((code & 7u) << 4));
  *(unsigned*)(img + byte) = u;
  if (tid == 0) outf[LOSS_OFF] = 0.0f;
}

// ---------------- K1: A-in-regs bf16 MFMA GEMM -> per-point top-4 codes -------
// 256 thr (4 waves), block = 128 pts x 1024 codes, K=256. 1024 blocks.
// Wave w owns pts [w*32, w*32+32): A frags in 64 VGPRs, loaded once.
// B: 16 chunks x 64 codes (32KB), double-buffered in LDS, 1 barrier/chunk.
extern "C" __global__ __launch_bounds__(256) void vq_r6_k1(const float* __restrict__ x,
                                                           const unsigned char* __restrict__ img,
                                                           u64* __restrict__ cand4) {
  __shared__ __attribute__((aligned(16))) char lds[65536];
  const int t = threadIdx.x;
  const int bid = blockIdx.x;     // 1024 blocks
  const int lane = t & 63;
  const int w = t >> 6;           // wave 0..3
  const int g = lane >> 4, c16 = lane & 15;

  // ---- stage A once: 128 pts x 256 d -> lds[pt][d] bf16, swizzled rows ----
  {
    const size_t xbase = (size_t)(bid >> 5) * 1048576u + (size_t)(bid & 31) * 128u;
    for (int i = 0; i < 64; ++i) {
      int P = i * 256 + t;              // [0, 16384)
      int ptl = P & 127, dp = P >> 7;   // d = 2*dp
      float x0 = x[xbase + (size_t)(2 * dp) * 4096u + (unsigned)ptl];
      float x1 = x[xbase + (size_t)(2 * dp + 1) * 4096u + (unsigned)ptl];
      unsigned u = ((unsigned)f2bf(x1) << 16) | (unsigned)f2bf(x0);
      *(unsigned*)(lds + ptl * 512 + ((dp * 4) ^ ((ptl & 7) << 4))) = u;
    }
  }
  __syncthreads();

  // ---- A frags to registers: a[m][ks], row = w*32 + m*16 + c16 ----
  short8 a[2][8];
#pragma unroll
  for (int m = 0; m < 2; ++m)
#pragma unroll
    for (int ks = 0; ks < 8; ++ks) {
      int r = w * 32 + m * 16 + c16;
      a[m][ks] = *(const short8*)(lds + r * 512 + ((ks * 64 + g * 16) ^ ((c16 & 7) << 4)));
    }
  __syncthreads();

  // ---- B chunk loop: double-buffered, prefetch via registers ----
  char* buf0 = lds;
  char* buf1 = lds + 32768;
  u32x4 st[8];
  {  // prologue: chunk 0 -> buf0
#pragma unroll
    for (int i = 0; i < 8; ++i)
      st[i] = *(const u32x4*)(img + (size_t)(i * 4096 + t * 16));
#pragma unroll
    for (int i = 0; i < 8; ++i)
      *(u32x4*)(buf0 + i * 4096 + t * 16) = st[i];
  }
  __syncthreads();

  // per-lane top-2 per slot s = m*4+i (8 points, fixed class c16)
  float t1[8], t2[8];
#pragma unroll
  for (int s = 0; s < 8; ++s) { t1[s] = -__builtin_inff(); t2[s] = -__builtin_inff(); }

  for (int kc = 0; kc < 16; ++kc) {
    const int cur = kc & 1;
    if (kc < 15) {  // issue next chunk's loads early (hide under MFMA)
      const unsigned char* src = img + (size_t)(kc + 1) * 32768u;
#pragma unroll
      for (int i = 0; i < 8; ++i)
        st[i] = *(const u32x4*)(src + (size_t)(i * 4096 + t * 16));
    }
    const char* B = cur ? buf1 : buf0;
#pragma unroll
    for (int n = 0; n < 4; ++n) {
      f32x4 acc0 = (f32x4){0.f, 0.f, 0.f, 0.f};
      f32x4 acc1 = (f32x4){0.f, 0.f, 0.f, 0.f};
      const int row = n * 16 + c16;
#pragma unroll
      for (int ks = 0; ks < 8; ++ks) {
        short8 b = *(const short8*)(B + row * 512 + ((ks * 64 + g * 16) ^ ((c16 & 7) << 4)));
        acc0 = __builtin_amdgcn_mfma_f32_16x16x32_bf16(a[0][ks], b, acc0, 0, 0, 0);
        acc1 = __builtin_amdgcn_mfma_f32_16x16x32_bf16(a[1][ks], b, acc1, 0, 0, 0);
      }
      const unsigned code = (unsigned)(kc * 64 + n * 16 + c16);
#pragma unroll
      for (int m = 0; m < 2; ++m)
#pragma unroll
        for (int i = 0; i < 4; ++i) {
          float v = (m == 0) ? acc0[i] : acc1[i];
          float kf = __uint_as_float((__float_as_uint(v) & 0xFFFFFC00u) | code);
          int s = m * 4 + i;
          float lo = fminf(t1[s], kf);
          t1[s] = fmaxf(t1[s], kf);
          t2[s] = fmaxf(t2[s], lo);
        }
    }
    if (kc < 15) {  // write prefetched chunk into the other buffer
      char* Bn = cur ? buf0 : buf1;
#pragma unroll
      for (int i = 0; i < 8; ++i)
        *(u32x4*)(Bn + i * 4096 + t * 16) = st[i];
    }
    __syncthreads();
  }

  // ---- merge: keys[pt][class][2] in LDS, then top-4 of 32 per point ----
  float* kk = (float*)lds;  // 128 pts * 32 floats = 16KB
#pragma unroll
  for (int m = 0; m < 2; ++m)
#pragma unroll
    for (int i = 0; i < 4; ++i) {
      int s = m * 4 + i;
      int pt = w * 32 + m * 16 + g * 4 + i;
      kk[pt * 32 + c16 * 2] = t1[s];
      kk[pt * 32 + c16 * 2 + 1] = t2[s];
    }
  __syncthreads();

  if (t < 128) {
    float f1 = -__builtin_inff(), f2v = f1, f3 = f1, f4 = f1;
#pragma unroll
    for (int j = 0; j < 32; ++j) {
      float v = kk[t * 32 + ((j + t) & 31)];
      float b1 = fminf(f1, v);   f1 = fmaxf(f1, v);
      float b2 = fminf(f2v, b1); f2v = fmaxf(f2v, b1);
      float b3 = fminf(f3, b2);  f3 = fmaxf(f3, b2);
      f4 = fmaxf(f4, b3);
    }
    u64 pk = (u64)(__float_as_uint(f1) & 1023u)
           | ((u64)(__float_as_uint(f2v) & 1023u) << 16)
           | ((u64)(__float_as_uint(f3) & 1023u) << 32)
           | ((u64)(__float_as_uint(f4) & 1023u) << 48);
    cand4[(size_t)bid * 128u + (unsigned)t] = pk;
  }
}

// ---------------- K2: exact np-f32 rescore -> f32 idx + loss partials ---------
extern "C" __global__ __launch_bounds__(256) void vq_r6_k2(const float* __restrict__ x,
                                                           const float* __restrict__ cb,
                                                           const u64* __restrict__ cand4,
                                                           float* __restrict__ outf) {
#pragma clang fp contract(off)
  __shared__ float red[4];
  const int t = threadIdx.x;
  const unsigned p = blockIdx.x * 256u + (unsigned)t;

  const u64 pk = cand4[p];
  const int c0 = (int)(pk & 1023u);
  const int c1 = (int)((pk >> 16) & 1023u);
  const int c2 = (int)((pk >> 32) & 1023u);
  const int c3 = (int)((pk >> 48) & 1023u);

  const size_t xoff = ((size_t)(p >> 12)) * 1048576u + (size_t)(p & 4095u);
  const float* e0 = cb + (size_t)c0 * 256u;
  const float* e1 = cb + (size_t)c1 * 256u;
  const float* e2 = cb + (size_t)c2 * 256u;
  const float* e3 = cb + (size_t)c3 * 256u;

  double dt0 = 0.0, dt1 = 0.0, dt2 = 0.0, dt3 = 0.0;
  float hs1[2], h0[2], h1[2], h2[2], h3[2];
#pragma unroll
  for (int half = 0; half < 2; ++half) {
    float r[8], a0[8], a1[8], a2[8], a3[8];
#pragma unroll
    for (int j = 0; j < 8; ++j) {  // numpy pairwise: accumulators seeded with a[0..7]
      const int d = half * 128 + j;
      const float xv = x[xoff + (size_t)d * 4096u];
      const float v0 = e0[d], v1 = e1[d], v2 = e2[d], v3 = e3[d];
      r[j]  = __fmul_rn(xv, xv);
      a0[j] = __fmul_rn(v0, v0);
      a1[j] = __fmul_rn(v1, v1);
      a2[j] = __fmul_rn(v2, v2);
      a3[j] = __fmul_rn(v3, v3);
      dt0 = fma((double)xv, (double)v0, dt0);
      dt1 = fma((double)xv, (double)v1, dt1);
      dt2 = fma((double)xv, (double)v2, dt2);
      dt3 = fma((double)xv, (double)v3, dt3);
    }
    for (int i = 8; i < 128; i += 8) {
#pragma unroll
      for (int j = 0; j < 8; ++j) {
        const int d = half * 128 + i + j;
        const float xv = x[xoff + (size_t)d * 4096u];
        const float v0 = e0[d], v1 = e1[d], v2 = e2[d], v3 = e3[d];
        r[j]  = __fadd_rn(r[j],  __fmul_rn(xv, xv));
        a0[j] = __fadd_rn(a0[j], __fmul_rn(v0, v0));
        a1[j] = __fadd_rn(a1[j], __fmul_rn(v1, v1));
        a2[j] = __fadd_rn(a2[j], __fmul_rn(v2, v2));
        a3[j] = __fadd_rn(a3[j], __fmul_rn(v3, v3));
        dt0 = fma((double)xv, (double)v0, dt0);
        dt1 = fma((double)xv, (double)v1, dt1);
        dt2 = fma((double)xv, (double)v2, dt2);
        dt3 = fma((double)xv, (double)v3, dt3);
      }
    }
    hs1[half] = COMB(r);
    h0[half] = COMB(a0); h1[half] = COMB(a1); h2[half] = COMB(a2); h3[half] = COMB(a3);
  }
  const float s1v = __fadd_rn(hs1[0], hs1[1]);
  const float s20 = __fadd_rn(h0[0], h0[1]);
  const float s21 = __fadd_rn(h1[0], h1[1]);
  const float s22 = __fadd_rn(h2[0], h2[1]);
  const float s23 = __fadd_rn(h3[0], h3[1]);

  float bestd = __builtin_inff();
  int besti = 0x7FFFFFFF;
  { float dd = __fsub_rn(__fadd_rn(s1v, s20), __fmul_rn(2.0f, (float)dt0));
    if (dd < bestd || (dd == bestd && c0 < besti)) { bestd = dd; besti = c0; } }
  { float dd = __fsub_rn(__fadd_rn(s1v, s21), __fmul_rn(2.0f, (float)dt1));
    if (dd < bestd || (dd == bestd && c1 < besti)) { bestd = dd; besti = c1; } }
  { float dd = __fsub_rn(__fadd_rn(s1v, s22), __fmul_rn(2.0f, (float)dt2));
    if (dd < bestd || (dd == bestd && c2 < besti)) { bestd = dd; besti = c2; } }
  { float dd = __fsub_rn(__fadd_rn(s1v, s23), __fmul_rn(2.0f, (float)dt3));
    if (dd < bestd || (dd == bestd && c3 < besti)) { bestd = dd; besti = c3; } }

  outf[IDX_OFF + p] = (float)besti;  // exact integer in f32

  float sum = bestd;  // loss partial: sum_c (x-q)^2 == s1 + s2 - 2*dot = bestd
#pragma unroll
  for (int off = 32; off > 0; off >>= 1) sum += __shfl_down(sum, off);
  if ((t & 63) == 0) red[t >> 6] = sum;
  __syncthreads();
  if (t == 0) atomicAdd(outf + LOSS_OFF, red[0] + red[1] + red[2] + red[3]);
}

// ---------------- K4: finalize loss in place -----------------------------------
extern "C" __global__ void vq_r6_k4(float* __restrict__ outf) {
  if (threadIdx.x == 0 && blockIdx.x == 0)
    outf[LOSS_OFF] = 2.0f * (outf[LOSS_OFF] / 33554432.0f);
}

// ---------------- K3: z_q output, write-only (z_q_st ~= q, err <= 2.4e-7) ------
extern "C" __global__ __launch_bounds__(256) void vq_r6_k3(const float* __restrict__ cb,
                                                           float* __restrict__ outf) {
  size_t tid = (size_t)blockIdx.x * 256u + threadIdx.x;  // 8388608 threads x 4 elems
  size_t e = tid * 4u;                                   // [0, 33554432)
  unsigned c = (unsigned)((e >> 12) & 255u);
  unsigned b = (unsigned)(e >> 20);
  unsigned hw = (unsigned)(e & 4095u);
  unsigned p = (b << 12) | hw;
  const float* idxf = outf + IDX_OFF;
  int i0 = ((int)idxf[p]) & 1023;
  int i1 = ((int)idxf[p + 1]) & 1023;
  int i2 = ((int)idxf[p + 2]) & 1023;
  int i3 = ((int)idxf[p + 3]) & 1023;
  float4 o;
  o.x = cb[(size_t)i0 * 256u + c];
  o.y = cb[(size_t)i1 * 256u + c];
  o.z = cb[(size_t)i2 * 256u + c];
  o.w = cb[(size_t)i3 * 256u + c];
  *(float4*)(outf + e) = o;
}

// ---------------- host ---------------------------------------------------------
extern "C" void kernel_launch(void* const* d_in, const int* in_sizes, int n_in,
                              void* d_out, int out_size, void* d_ws, size_t ws_size,
                              hipStream_t stream) {
  const float* x = (const float*)d_in[0];   // [32,256,64,64] f32
  const float* cb = (const float*)d_in[1];  // [1024,256] f32
  float* outf = (float*)d_out;              // f32 outputs
  unsigned char* img = (unsigned char*)d_out + IMG_BYTE;   // scratch in z_q region
  u64* cand4 = (u64*)((unsigned char*)d_out + CAND_BYTE);  // scratch in z_q region
  (void)in_sizes; (void)n_in; (void)out_size; (void)d_ws; (void)ws_size;

  vq_r6_k0<<<512, 256, 0, stream>>>(cb, img, outf);
  vq_r6_k1<<<1024, 256, 0, stream>>>(x, img, cand4);
  vq_r6_k2<<<512, 256, 0, stream>>>(x, cb, cand4, outf);
  vq_r6_k4<<<1, 64, 0, stream>>>(outf);
  vq_r6_k3<<<32768, 256, 0, stream>>>(cb, outf);
}

// Round 7
// 261.008 us; speedup vs baseline: 1.5716x; 1.2085x over previous
//
#include <hip/hip_runtime.h>

// VectorQuantizer on MI355X (gfx950). Round 7: conflict-free fragment-order B,
// m=4 reuse in K1; precomputed exact codebook norms; LDS-staged K3.
// d_out (f32): [z_q 33554432][idx 131072][loss 1]  (out_size 33685505)
// Scratch inside z_q's byte region (overwritten by K3 at the end):
//   bytes [67108864, 67633152)  bf16 codebook image in MFMA-fragment order
//   bytes [68157440, 69206016)  cand4: u64[131072] packed top-4 codes
//   bytes [69206016, 69210112)  enrm: f32[1024] exact np-pairwise codebook norms
// Loss slot outf[33685504] = accumulator (K0 zeroes, K2 adds, K4 rescales).

typedef __attribute__((ext_vector_type(8))) short short8;
typedef __attribute__((ext_vector_type(4))) float f32x4;
typedef __attribute__((ext_vector_type(4))) unsigned int u32x4;
typedef unsigned long long u64;

#define IDX_OFF   33554432u
#define LOSS_OFF  33685504u
#define IMG_BYTE  67108864u
#define CAND_BYTE 68157440u
#define ENRM_BYTE 69206016u

__device__ __forceinline__ unsigned short f2bf(float f) {
  unsigned u = __float_as_uint(f);
  unsigned r = (u + 0x7FFFu + ((u >> 16) & 1u)) >> 16;  // RNE
  return (unsigned short)r;
}

// numpy pairwise combine of 8 accumulators
#define COMB(r) __fadd_rn(__fadd_rn(__fadd_rn(r[0], r[1]), __fadd_rn(r[2], r[3])), \
                          __fadd_rn(__fadd_rn(r[4], r[5]), __fadd_rn(r[6], r[7])))

// ---------------- K0: codebook image in MFMA-fragment order + zero loss -------
// img layout: 16B at ((kc*4+n)*8+ks)*1024 + lane*16 holds codes kc*64+n*16+(lane&15),
// d = ks*32 + (lane>>4)*8 + 0..7  (so every K1 B-frag read is contiguous 1KB/wave).
extern "C" __global__ __launch_bounds__(256) void vq_r7_k0(const float* __restrict__ cb,
                                                           unsigned char* __restrict__ img,
                                                           float* __restrict__ outf) {
  unsigned tid = blockIdx.x * 256u + threadIdx.x;  // 131072 = (code, dpair)
  unsigned code = tid >> 7, dp = tid & 127u;
  const float* p = cb + (size_t)code * 256u + dp * 2u;
  unsigned u = ((unsigned)f2bf(p[1]) << 16) | (unsigned)f2bf(p[0]);
  unsigned kc = code >> 6, n = (code >> 4) & 3, c16 = code & 15;
  unsigned ks = dp >> 4, g = (dp >> 2) & 3, j = dp & 3;
  unsigned byte = kc * 32768u + (n * 8u + ks) * 1024u + (g * 16u + c16) * 16u + j * 4u;
  *(unsigned*)(img + byte) = u;
  if (tid == 0) outf[LOSS_OFF] = 0.0f;
}

// ---------------- K0b: exact np-f32 pairwise codebook norms -------------------
extern "C" __global__ __launch_bounds__(256) void vq_r7_k0b(const float* __restrict__ cb,
                                                            float* __restrict__ enrm) {
#pragma clang fp contract(off)
  int c = blockIdx.x * 256 + threadIdx.x;  // 4 blocks -> 1024 codes
  const float* e = cb + (size_t)c * 256u;
  float h[2];
#pragma unroll
  for (int half = 0; half < 2; ++half) {
    float r[8];
#pragma unroll
    for (int j = 0; j < 8; ++j) {
      float v = e[half * 128 + j];
      r[j] = __fmul_rn(v, v);
    }
    for (int i = 8; i < 128; i += 8) {
#pragma unroll
      for (int j = 0; j < 8; ++j) {
        float v = e[half * 128 + i + j];
        r[j] = __fadd_rn(r[j], __fmul_rn(v, v));
      }
    }
    h[half] = COMB(r);
  }
  enrm[c] = __fadd_rn(h[0], h[1]);
}

// ---------------- K1: A-in-regs (m=4) MFMA GEMM, conflict-free B --------------
// 256 thr (4 waves), block = 256 pts x 1024 codes, 512 blocks. Wave owns 64 pts.
// B: 16 chunks x 64 codes, fragment-order, double-buffered, 1 barrier/chunk.
extern "C" __global__ __launch_bounds__(256, 2) void vq_r7_k1(const float* __restrict__ x,
                                                              const unsigned char* __restrict__ img,
                                                              u64* __restrict__ cand4) {
  __shared__ __attribute__((aligned(16))) char lds[65536];
  const int t = threadIdx.x;
  const int bid = blockIdx.x;  // 512 blocks
  const int lane = t & 63;
  const int w = t >> 6;
  const int g = lane >> 4, c16 = lane & 15;

  const size_t xbase = (size_t)(bid >> 4) * 1048576u + (size_t)(bid & 15) * 256u;

  // ---- A: two halves of 128 pts staged via LDS transpose, frags to regs ----
  short8 a[4][8];
  for (int h = 0; h < 2; ++h) {
    for (int i = 0; i < 64; ++i) {
      int P = i * 256 + t;               // 128 pts x 128 dpairs
      int ptl = P & 127, dp = P >> 7;
      float x0 = x[xbase + (size_t)(2 * dp) * 4096u + (unsigned)(h * 128 + ptl)];
      float x1 = x[xbase + (size_t)(2 * dp + 1) * 4096u + (unsigned)(h * 128 + ptl)];
      unsigned u = ((unsigned)f2bf(x1) << 16) | (unsigned)f2bf(x0);
      // 4B-granular XOR: write banks = dp ^ (ptl&31) -> conflict-free writes
      *(unsigned*)(lds + ptl * 512 + ((dp * 4) ^ ((ptl & 31) << 2))) = u;
    }
    __syncthreads();
    if ((w >> 1) == h) {
      const int rbase = (w & 1) * 64;
#pragma unroll
      for (int m = 0; m < 4; ++m) {
        const int r = rbase + m * 16 + c16;
        const int rsw = (r & 31) << 2;
#pragma unroll
        for (int ks = 0; ks < 8; ++ks) {
          union { unsigned q[4]; short8 s; } uu;
#pragma unroll
          for (int jj = 0; jj < 4; ++jj)
            uu.q[jj] = *(const unsigned*)(lds + r * 512 + (((ks * 16 + g * 4 + jj) * 4) ^ rsw));
          a[m][ks] = uu.s;
        }
      }
    }
    __syncthreads();
  }

  // ---- B chunk loop: fragment-order flat copy, double-buffered ----
  char* buf0 = lds;
  char* buf1 = lds + 32768;
  u32x4 st[8];
#pragma unroll
  for (int i = 0; i < 8; ++i)
    st[i] = *(const u32x4*)(img + (size_t)((i * 256 + t) * 16));
#pragma unroll
  for (int i = 0; i < 8; ++i)
    *(u32x4*)(buf0 + (i * 256 + t) * 16) = st[i];
  __syncthreads();

  float t1[16], t2[16];
#pragma unroll
  for (int s = 0; s < 16; ++s) { t1[s] = -__builtin_inff(); t2[s] = -__builtin_inff(); }

  int cur = 0;
  for (int kc = 0; kc < 16; ++kc) {
    if (kc < 15) {
      const unsigned char* src = img + (size_t)(kc + 1) * 32768u;
#pragma unroll
      for (int i = 0; i < 8; ++i)
        st[i] = *(const u32x4*)(src + (size_t)((i * 256 + t) * 16));
    }
    const char* B = cur ? buf1 : buf0;
#pragma unroll
    for (int n = 0; n < 4; ++n) {
      f32x4 acc0 = (f32x4){0.f, 0.f, 0.f, 0.f};
      f32x4 acc1 = (f32x4){0.f, 0.f, 0.f, 0.f};
      f32x4 acc2 = (f32x4){0.f, 0.f, 0.f, 0.f};
      f32x4 acc3 = (f32x4){0.f, 0.f, 0.f, 0.f};
#pragma unroll
      for (int ks = 0; ks < 8; ++ks) {
        short8 b = *(const short8*)(B + (n * 8 + ks) * 1024 + lane * 16);  // contiguous 1KB/wave
        acc0 = __builtin_amdgcn_mfma_f32_16x16x32_bf16(a[0][ks], b, acc0, 0, 0, 0);
        acc1 = __builtin_amdgcn_mfma_f32_16x16x32_bf16(a[1][ks], b, acc1, 0, 0, 0);
        acc2 = __builtin_amdgcn_mfma_f32_16x16x32_bf16(a[2][ks], b, acc2, 0, 0, 0);
        acc3 = __builtin_amdgcn_mfma_f32_16x16x32_bf16(a[3][ks], b, acc3, 0, 0, 0);
      }
      const unsigned code = (unsigned)(kc * 64 + n * 16 + c16);
#define SCRN(v, s) { float kf = __uint_as_float((__float_as_uint(v) & 0xFFFFFC00u) | code); \
                     t2[s] = __builtin_amdgcn_fmed3f(kf, t1[s], t2[s]); \
                     t1[s] = fmaxf(t1[s], kf); }
#pragma unroll
      for (int i = 0; i < 4; ++i) {
        SCRN(acc0[i], i);
        SCRN(acc1[i], 4 + i);
        SCRN(acc2[i], 8 + i);
        SCRN(acc3[i], 12 + i);
      }
#undef SCRN
    }
    if (kc < 15) {
      char* Bn = cur ? buf0 : buf1;
#pragma unroll
      for (int i = 0; i < 8; ++i)
        *(u32x4*)(Bn + (i * 256 + t) * 16) = st[i];
    }
    __syncthreads();
    cur ^= 1;
  }

  // ---- merge: kk[pt][class][2] (16 classes = c16), then top-4 of 32 ----
  float* kk = (float*)lds;  // 256 pts x 32 floats = 32KB (buf0 region, safe)
#pragma unroll
  for (int m = 0; m < 4; ++m)
#pragma unroll
    for (int i = 0; i < 4; ++i) {
      int pt = w * 64 + m * 16 + g * 4 + i;
      kk[pt * 32 + c16 * 2] = t1[m * 4 + i];
      kk[pt * 32 + c16 * 2 + 1] = t2[m * 4 + i];
    }
  __syncthreads();

  {
    float f1 = -__builtin_inff(), f2v = f1, f3 = f1, f4 = f1;
#pragma unroll
    for (int j = 0; j < 32; ++j) {
      float v = kk[t * 32 + ((j + t) & 31)];
      float b1 = fminf(f1, v);   f1 = fmaxf(f1, v);
      float b2 = fminf(f2v, b1); f2v = fmaxf(f2v, b1);
      float b3 = fminf(f3, b2);  f3 = fmaxf(f3, b2);
      f4 = fmaxf(f4, b3);
    }
    u64 pk = (u64)(__float_as_uint(f1) & 1023u)
           | ((u64)(__float_as_uint(f2v) & 1023u) << 16)
           | ((u64)(__float_as_uint(f3) & 1023u) << 32)
           | ((u64)(__float_as_uint(f4) & 1023u) << 48);
    cand4[(size_t)bid * 256u + (unsigned)t] = pk;
  }
}

// ---------------- K2: exact np-f32 rescore (norms precomputed) ----------------
extern "C" __global__ __launch_bounds__(256) void vq_r7_k2(const float* __restrict__ x,
                                                           const float* __restrict__ cb,
                                                           const u64* __restrict__ cand4,
                                                           const float* __restrict__ enrm,
                                                           float* __restrict__ outf) {
#pragma clang fp contract(off)
  __shared__ float red[4];
  const int t = threadIdx.x;
  const unsigned p = blockIdx.x * 256u + (unsigned)t;

  const u64 pk = cand4[p];
  const int c0 = (int)(pk & 1023u);
  const int c1 = (int)((pk >> 16) & 1023u);
  const int c2 = (int)((pk >> 32) & 1023u);
  const int c3 = (int)((pk >> 48) & 1023u);

  const size_t xoff = ((size_t)(p >> 12)) * 1048576u + (size_t)(p & 4095u);
  const float* e0 = cb + (size_t)c0 * 256u;
  const float* e1 = cb + (size_t)c1 * 256u;
  const float* e2 = cb + (size_t)c2 * 256u;
  const float* e3 = cb + (size_t)c3 * 256u;

  double dt0 = 0.0, dt1 = 0.0, dt2 = 0.0, dt3 = 0.0;
  float hs1[2];
#pragma unroll
  for (int half = 0; half < 2; ++half) {
    float r[8];
#pragma unroll
    for (int j = 0; j < 8; ++j) {  // numpy pairwise: accumulators seeded with a[0..7]
      const int d = half * 128 + j;
      const float xv = x[xoff + (size_t)d * 4096u];
      r[j] = __fmul_rn(xv, xv);
      dt0 = fma((double)xv, (double)e0[d], dt0);
      dt1 = fma((double)xv, (double)e1[d], dt1);
      dt2 = fma((double)xv, (double)e2[d], dt2);
      dt3 = fma((double)xv, (double)e3[d], dt3);
    }
    for (int i = 8; i < 128; i += 8) {
#pragma unroll
      for (int j = 0; j < 8; ++j) {
        const int d = half * 128 + i + j;
        const float xv = x[xoff + (size_t)d * 4096u];
        r[j] = __fadd_rn(r[j], __fmul_rn(xv, xv));
        dt0 = fma((double)xv, (double)e0[d], dt0);
        dt1 = fma((double)xv, (double)e1[d], dt1);
        dt2 = fma((double)xv, (double)e2[d], dt2);
        dt3 = fma((double)xv, (double)e3[d], dt3);
      }
    }
    hs1[half] = COMB(r);
  }
  const float s1v = __fadd_rn(hs1[0], hs1[1]);
  const float s20 = enrm[c0];
  const float s21 = enrm[c1];
  const float s22 = enrm[c2];
  const float s23 = enrm[c3];

  float bestd = __builtin_inff();
  int besti = 0x7FFFFFFF;
  { float dd = __fsub_rn(__fadd_rn(s1v, s20), __fmul_rn(2.0f, (float)dt0));
    if (dd < bestd || (dd == bestd && c0 < besti)) { bestd = dd; besti = c0; } }
  { float dd = __fsub_rn(__fadd_rn(s1v, s21), __fmul_rn(2.0f, (float)dt1));
    if (dd < bestd || (dd == bestd && c1 < besti)) { bestd = dd; besti = c1; } }
  { float dd = __fsub_rn(__fadd_rn(s1v, s22), __fmul_rn(2.0f, (float)dt2));
    if (dd < bestd || (dd == bestd && c2 < besti)) { bestd = dd; besti = c2; } }
  { float dd = __fsub_rn(__fadd_rn(s1v, s23), __fmul_rn(2.0f, (float)dt3));
    if (dd < bestd || (dd == bestd && c3 < besti)) { bestd = dd; besti = c3; } }

  outf[IDX_OFF + p] = (float)besti;  // exact integer in f32

  float sum = bestd;  // loss partial: sum_c (x-q)^2 == s1 + s2 - 2*dot = bestd
#pragma unroll
  for (int off = 32; off > 0; off >>= 1) sum += __shfl_down(sum, off);
  if ((t & 63) == 0) red[t >> 6] = sum;
  __syncthreads();
  if (t == 0) atomicAdd(outf + LOSS_OFF, red[0] + red[1] + red[2] + red[3]);
}

// ---------------- K4: finalize loss in place -----------------------------------
extern "C" __global__ void vq_r7_k4(float* __restrict__ outf) {
  if (threadIdx.x == 0 && blockIdx.x == 0)
    outf[LOSS_OFF] = 2.0f * (outf[LOSS_OFF] / 33554432.0f);
}

// ---------------- K3: z_q via LDS-staged codebook rows, coalesced writes -------
extern "C" __global__ __launch_bounds__(256) void vq_r7_k3(const float* __restrict__ cb,
                                                           float* __restrict__ outf) {
  __shared__ float rows[32 * 257];  // +1-pad: conflict-free column re-read
  const int t = threadIdx.x;
  const unsigned p0 = blockIdx.x * 32u;  // 4096 blocks x 32 points
  const unsigned b = p0 >> 12, hw0 = p0 & 4095u;
  const float* idxf = outf + IDX_OFF;
  for (int i = 0; i < 32; ++i) {
    int row = ((int)idxf[p0 + (unsigned)i]) & 1023;  // broadcast load
    rows[i * 257 + t] = cb[(size_t)row * 256u + (unsigned)t];
  }
  __syncthreads();
  const int j = t & 31, chh = t >> 5;
  float* obase = outf + (size_t)b * 1048576u + hw0 + (unsigned)j;
#pragma unroll
  for (int cc = 0; cc < 32; ++cc) {
    int c = chh * 32 + cc;
    obase[(size_t)c * 4096u] = rows[j * 257 + c];
  }
}

// ---------------- host ---------------------------------------------------------
extern "C" void kernel_launch(void* const* d_in, const int* in_sizes, int n_in,
                              void* d_out, int out_size, void* d_ws, size_t ws_size,
                              hipStream_t stream) {
  const float* x = (const float*)d_in[0];   // [32,256,64,64] f32
  const float* cb = (const float*)d_in[1];  // [1024,256] f32
  float* outf = (float*)d_out;              // f32 outputs
  unsigned char* img = (unsigned char*)d_out + IMG_BYTE;
  u64* cand4 = (u64*)((unsigned char*)d_out + CAND_BYTE);
  float* enrm = (float*)((unsigned char*)d_out + ENRM_BYTE);
  (void)in_sizes; (void)n_in; (void)out_size; (void)d_ws; (void)ws_size;

  vq_r7_k0<<<512, 256, 0, stream>>>(cb, img, outf);
  vq_r7_k0b<<<4, 256, 0, stream>>>(cb, enrm);
  vq_r7_k1<<<512, 256, 0, stream>>>(x, img, cand4);
  vq_r7_k2<<<512, 256, 0, stream>>>(x, cb, cand4, enrm, outf);
  vq_r7_k4<<<1, 64, 0, stream>>>(outf);
  vq_r7_k3<<<4096, 256, 0, stream>>>(cb, outf);
}

// Round 8
// 259.548 us; speedup vs baseline: 1.5805x; 1.0056x over previous
//
#include <hip/hip_runtime.h>

// VectorQuantizer on MI355X (gfx950). Round 7: conflict-free fragment-order B,
// m=4 reuse in K1; precomputed exact codebook norms; LDS-staged K3.
// d_out (f32): [z_q 33554432][idx 131072][loss 1]  (out_size 33685505)
// Scratch inside z_q's byte region (overwritten by K3 at the end):
//   bytes [67108864, 67633152)  bf16 codebook image in MFMA-fragment order
//   bytes [68157440, 69206016)  cand4: u64[131072] packed top-4 codes
//   bytes [69206016, 69210112)  enrm: f32[1024] exact np-pairwise codebook norms
// Loss slot outf[33685504] = accumulator (K0 zeroes, K2 adds, K4 rescales).

typedef __attribute__((ext_vector_type(8))) short short8;
typedef __attribute__((ext_vector_type(4))) float f32x4;
typedef __attribute__((ext_vector_type(4))) unsigned int u32x4;
typedef unsigned long long u64;

#define IDX_OFF   33554432u
#define LOSS_OFF  33685504u
#define IMG_BYTE  67108864u
#define CAND_BYTE 68157440u
#define ENRM_BYTE 69206016u

__device__ __forceinline__ unsigned short f2bf(float f) {
  unsigned u = __float_as_uint(f);
  unsigned r = (u + 0x7FFFu + ((u >> 16) & 1u)) >> 16;  // RNE
  return (unsigned short)r;
}

// numpy pairwise combine of 8 accumulators
#define COMB(r) __fadd_rn(__fadd_rn(__fadd_rn(r[0], r[1]), __fadd_rn(r[2], r[3])), \
                          __fadd_rn(__fadd_rn(r[4], r[5]), __fadd_rn(r[6], r[7])))

// ---------------- K0: codebook image in MFMA-fragment order + zero loss -------
// img layout: 16B at ((kc*4+n)*8+ks)*1024 + lane*16 holds codes kc*64+n*16+(lane&15),
// d = ks*32 + (lane>>4)*8 + 0..7  (so every K1 B-frag read is contiguous 1KB/wave).
extern "C" __global__ __launch_bounds__(256) void vq_r7_k0(const float* __restrict__ cb,
                                                           unsigned char* __restrict__ img,
                                                           float* __restrict__ outf) {
  unsigned tid = blockIdx.x * 256u + threadIdx.x;  // 131072 = (code, dpair)
  unsigned code = tid >> 7, dp = tid & 127u;
  const float* p = cb + (size_t)code * 256u + dp * 2u;
  unsigned u = ((unsigned)f2bf(p[1]) << 16) | (unsigned)f2bf(p[0]);
  unsigned kc = code >> 6, n = (code >> 4) & 3, c16 = code & 15;
  unsigned ks = dp >> 4, g = (dp >> 2) & 3, j = dp & 3;
  unsigned byte = kc * 32768u + (n * 8u + ks) * 1024u + (g * 16u + c16) * 16u + j * 4u;
  *(unsigned*)(img + byte) = u;
  if (tid == 0) outf[LOSS_OFF] = 0.0f;
}

// ---------------- K0b: exact np-f32 pairwise codebook norms -------------------
extern "C" __global__ __launch_bounds__(256) void vq_r7_k0b(const float* __restrict__ cb,
                                                            float* __restrict__ enrm) {
#pragma clang fp contract(off)
  int c = blockIdx.x * 256 + threadIdx.x;  // 4 blocks -> 1024 codes
  const float* e = cb + (size_t)c * 256u;
  float h[2];
#pragma unroll
  for (int half = 0; half < 2; ++half) {
    float r[8];
#pragma unroll
    for (int j = 0; j < 8; ++j) {
      float v = e[half * 128 + j];
      r[j] = __fmul_rn(v, v);
    }
    for (int i = 8; i < 128; i += 8) {
#pragma unroll
      for (int j = 0; j < 8; ++j) {
        float v = e[half * 128 + i + j];
        r[j] = __fadd_rn(r[j], __fmul_rn(v, v));
      }
    }
    h[half] = COMB(r);
  }
  enrm[c] = __fadd_rn(h[0], h[1]);
}

// ---------------- K1: A-in-regs (m=4) MFMA GEMM, conflict-free B --------------
// 256 thr (4 waves), block = 256 pts x 1024 codes, 512 blocks. Wave owns 64 pts.
// B: 16 chunks x 64 codes, fragment-order, double-buffered, 1 barrier/chunk.
extern "C" __global__ __launch_bounds__(256, 2) void vq_r7_k1(const float* __restrict__ x,
                                                              const unsigned char* __restrict__ img,
                                                              u64* __restrict__ cand4) {
  __shared__ __attribute__((aligned(16))) char lds[65536];
  const int t = threadIdx.x;
  const int bid = blockIdx.x;  // 512 blocks
  const int lane = t & 63;
  const int w = t >> 6;
  const int g = lane >> 4, c16 = lane & 15;

  const size_t xbase = (size_t)(bid >> 4) * 1048576u + (size_t)(bid & 15) * 256u;

  // ---- A: two halves of 128 pts staged via LDS transpose, frags to regs ----
  short8 a[4][8];
  for (int h = 0; h < 2; ++h) {
    for (int i = 0; i < 64; ++i) {
      int P = i * 256 + t;               // 128 pts x 128 dpairs
      int ptl = P & 127, dp = P >> 7;
      float x0 = x[xbase + (size_t)(2 * dp) * 4096u + (unsigned)(h * 128 + ptl)];
      float x1 = x[xbase + (size_t)(2 * dp + 1) * 4096u + (unsigned)(h * 128 + ptl)];
      unsigned u = ((unsigned)f2bf(x1) << 16) | (unsigned)f2bf(x0);
      // 4B-granular XOR: write banks = dp ^ (ptl&31) -> conflict-free writes
      *(unsigned*)(lds + ptl * 512 + ((dp * 4) ^ ((ptl & 31) << 2))) = u;
    }
    __syncthreads();
    if ((w >> 1) == h) {
      const int rbase = (w & 1) * 64;
#pragma unroll
      for (int m = 0; m < 4; ++m) {
        const int r = rbase + m * 16 + c16;
        const int rsw = (r & 31) << 2;
#pragma unroll
        for (int ks = 0; ks < 8; ++ks) {
          union { unsigned q[4]; short8 s; } uu;
#pragma unroll
          for (int jj = 0; jj < 4; ++jj)
            uu.q[jj] = *(const unsigned*)(lds + r * 512 + (((ks * 16 + g * 4 + jj) * 4) ^ rsw));
          a[m][ks] = uu.s;
        }
      }
    }
    __syncthreads();
  }

  // ---- B chunk loop: fragment-order flat copy, double-buffered ----
  char* buf0 = lds;
  char* buf1 = lds + 32768;
  u32x4 st[8];
#pragma unroll
  for (int i = 0; i < 8; ++i)
    st[i] = *(const u32x4*)(img + (size_t)((i * 256 + t) * 16));
#pragma unroll
  for (int i = 0; i < 8; ++i)
    *(u32x4*)(buf0 + (i * 256 + t) * 16) = st[i];
  __syncthreads();

  float t1[16], t2[16];
#pragma unroll
  for (int s = 0; s < 16; ++s) { t1[s] = -__builtin_inff(); t2[s] = -__builtin_inff(); }

  int cur = 0;
  for (int kc = 0; kc < 16; ++kc) {
    if (kc < 15) {
      const unsigned char* src = img + (size_t)(kc + 1) * 32768u;
#pragma unroll
      for (int i = 0; i < 8; ++i)
        st[i] = *(const u32x4*)(src + (size_t)((i * 256 + t) * 16));
    }
    const char* B = cur ? buf1 : buf0;
#pragma unroll
    for (int n = 0; n < 4; ++n) {
      f32x4 acc0 = (f32x4){0.f, 0.f, 0.f, 0.f};
      f32x4 acc1 = (f32x4){0.f, 0.f, 0.f, 0.f};
      f32x4 acc2 = (f32x4){0.f, 0.f, 0.f, 0.f};
      f32x4 acc3 = (f32x4){0.f, 0.f, 0.f, 0.f};
#pragma unroll
      for (int ks = 0; ks < 8; ++ks) {
        short8 b = *(const short8*)(B + (n * 8 + ks) * 1024 + lane * 16);  // contiguous 1KB/wave
        acc0 = __builtin_amdgcn_mfma_f32_16x16x32_bf16(a[0][ks], b, acc0, 0, 0, 0);
        acc1 = __builtin_amdgcn_mfma_f32_16x16x32_bf16(a[1][ks], b, acc1, 0, 0, 0);
        acc2 = __builtin_amdgcn_mfma_f32_16x16x32_bf16(a[2][ks], b, acc2, 0, 0, 0);
        acc3 = __builtin_amdgcn_mfma_f32_16x16x32_bf16(a[3][ks], b, acc3, 0, 0, 0);
      }
      const unsigned code = (unsigned)(kc * 64 + n * 16 + c16);
#define SCRN(v, s) { float kf = __uint_as_float((__float_as_uint(v) & 0xFFFFFC00u) | code); \
                     t2[s] = __builtin_amdgcn_fmed3f(kf, t1[s], t2[s]); \
                     t1[s] = fmaxf(t1[s], kf); }
#pragma unroll
      for (int i = 0; i < 4; ++i) {
        SCRN(acc0[i], i);
        SCRN(acc1[i], 4 + i);
        SCRN(acc2[i], 8 + i);
        SCRN(acc3[i], 12 + i);
      }
#undef SCRN
    }
    if (kc < 15) {
      char* Bn = cur ? buf0 : buf1;
#pragma unroll
      for (int i = 0; i < 8; ++i)
        *(u32x4*)(Bn + (i * 256 + t) * 16) = st[i];
    }
    __syncthreads();
    cur ^= 1;
  }

  // ---- merge: kk[pt][class][2] (16 classes = c16), then top-4 of 32 ----
  float* kk = (float*)lds;  // 256 pts x 32 floats = 32KB (buf0 region, safe)
#pragma unroll
  for (int m = 0; m < 4; ++m)
#pragma unroll
    for (int i = 0; i < 4; ++i) {
      int pt = w * 64 + m * 16 + g * 4 + i;
      kk[pt * 32 + c16 * 2] = t1[m * 4 + i];
      kk[pt * 32 + c16 * 2 + 1] = t2[m * 4 + i];
    }
  __syncthreads();

  {
    float f1 = -__builtin_inff(), f2v = f1, f3 = f1, f4 = f1;
#pragma unroll
    for (int j = 0; j < 32; ++j) {
      float v = kk[t * 32 + ((j + t) & 31)];
      float b1 = fminf(f1, v);   f1 = fmaxf(f1, v);
      float b2 = fminf(f2v, b1); f2v = fmaxf(f2v, b1);
      float b3 = fminf(f3, b2);  f3 = fmaxf(f3, b2);
      f4 = fmaxf(f4, b3);
    }
    u64 pk = (u64)(__float_as_uint(f1) & 1023u)
           | ((u64)(__float_as_uint(f2v) & 1023u) << 16)
           | ((u64)(__float_as_uint(f3) & 1023u) << 32)
           | ((u64)(__float_as_uint(f4) & 1023u) << 48);
    cand4[(size_t)bid * 256u + (unsigned)t] = pk;
  }
}

// ---------------- K2: exact np-f32 rescore (norms precomputed) ----------------
extern "C" __global__ __launch_bounds__(256) void vq_r7_k2(const float* __restrict__ x,
                                                           const float* __restrict__ cb,
                                                           const u64* __restrict__ cand4,
                                                           const float* __restrict__ enrm,
                                                           float* __restrict__ outf) {
#pragma clang fp contract(off)
  __shared__ float red[4];
  const int t = threadIdx.x;
  const unsigned p = blockIdx.x * 256u + (unsigned)t;

  const u64 pk = cand4[p];
  const int c0 = (int)(pk & 1023u);
  const int c1 = (int)((pk >> 16) & 1023u);
  const int c2 = (int)((pk >> 32) & 1023u);
  const int c3 = (int)((pk >> 48) & 1023u);

  const size_t xoff = ((size_t)(p >> 12)) * 1048576u + (size_t)(p & 4095u);
  const float* e0 = cb + (size_t)c0 * 256u;
  const float* e1 = cb + (size_t)c1 * 256u;
  const float* e2 = cb + (size_t)c2 * 256u;
  const float* e3 = cb + (size_t)c3 * 256u;

  double dt0 = 0.0, dt1 = 0.0, dt2 = 0.0, dt3 = 0.0;
  float hs1[2];
#pragma unroll
  for (int half = 0; half < 2; ++half) {
    float r[8];
#pragma unroll
    for (int j = 0; j < 8; ++j) {  // numpy pairwise: accumulators seeded with a[0..7]
      const int d = half * 128 + j;
      const float xv = x[xoff + (size_t)d * 4096u];
      r[j] = __fmul_rn(xv, xv);
      dt0 = fma((double)xv, (double)e0[d], dt0);
      dt1 = fma((double)xv, (double)e1[d], dt1);
      dt2 = fma((double)xv, (double)e2[d], dt2);
      dt3 = fma((double)xv, (double)e3[d], dt3);
    }
    for (int i = 8; i < 128; i += 8) {
#pragma unroll
      for (int j = 0; j < 8; ++j) {
        const int d = half * 128 + i + j;
        const float xv = x[xoff + (size_t)d * 4096u];
        r[j] = __fadd_rn(r[j], __fmul_rn(xv, xv));
        dt0 = fma((double)xv, (double)e0[d], dt0);
        dt1 = fma((double)xv, (double)e1[d], dt1);
        dt2 = fma((double)xv, (double)e2[d], dt2);
        dt3 = fma((double)xv, (double)e3[d], dt3);
      }
    }
    hs1[half] = COMB(r);
  }
  const float s1v = __fadd_rn(hs1[0], hs1[1]);
  const float s20 = enrm[c0];
  const float s21 = enrm[c1];
  const float s22 = enrm[c2];
  const float s23 = enrm[c3];

  float bestd = __builtin_inff();
  int besti = 0x7FFFFFFF;
  { float dd = __fsub_rn(__fadd_rn(s1v, s20), __fmul_rn(2.0f, (float)dt0));
    if (dd < bestd || (dd == bestd && c0 < besti)) { bestd = dd; besti = c0; } }
  { float dd = __fsub_rn(__fadd_rn(s1v, s21), __fmul_rn(2.0f, (float)dt1));
    if (dd < bestd || (dd == bestd && c1 < besti)) { bestd = dd; besti = c1; } }
  { float dd = __fsub_rn(__fadd_rn(s1v, s22), __fmul_rn(2.0f, (float)dt2));
    if (dd < bestd || (dd == bestd && c2 < besti)) { bestd = dd; besti = c2; } }
  { float dd = __fsub_rn(__fadd_rn(s1v, s23), __fmul_rn(2.0f, (float)dt3));
    if (dd < bestd || (dd == bestd && c3 < besti)) { bestd = dd; besti = c3; } }

  outf[IDX_OFF + p] = (float)besti;  // exact integer in f32

  float sum = bestd;  // loss partial: sum_c (x-q)^2 == s1 + s2 - 2*dot = bestd
#pragma unroll
  for (int off = 32; off > 0; off >>= 1) sum += __shfl_down(sum, off);
  if ((t & 63) == 0) red[t >> 6] = sum;
  __syncthreads();
  if (t == 0) atomicAdd(outf + LOSS_OFF, red[0] + red[1] + red[2] + red[3]);
}

// ---------------- K4: finalize loss in place -----------------------------------
extern "C" __global__ void vq_r7_k4(float* __restrict__ outf) {
  if (threadIdx.x == 0 && blockIdx.x == 0)
    outf[LOSS_OFF] = 2.0f * (outf[LOSS_OFF] / 33554432.0f);
}

// ---------------- K3: z_q via LDS-staged codebook rows, coalesced writes -------
extern "C" __global__ __launch_bounds__(256) void vq_r7_k3(const float* __restrict__ cb,
                                                           float* __restrict__ outf) {
  __shared__ float rows[32 * 257];  // +1-pad: conflict-free column re-read
  const int t = threadIdx.x;
  const unsigned p0 = blockIdx.x * 32u;  // 4096 blocks x 32 points
  const unsigned b = p0 >> 12, hw0 = p0 & 4095u;
  const float* idxf = outf + IDX_OFF;
  for (int i = 0; i < 32; ++i) {
    int row = ((int)idxf[p0 + (unsigned)i]) & 1023;  // broadcast load
    rows[i * 257 + t] = cb[(size_t)row * 256u + (unsigned)t];
  }
  __syncthreads();
  const int j = t & 31, chh = t >> 5;
  float* obase = outf + (size_t)b * 1048576u + hw0 + (unsigned)j;
#pragma unroll
  for (int cc = 0; cc < 32; ++cc) {
    int c = chh * 32 + cc;
    obase[(size_t)c * 4096u] = rows[j * 257 + c];
  }
}

// ---------------- host ---------------------------------------------------------
extern "C" void kernel_launch(void* const* d_in, const int* in_sizes, int n_in,
                              void* d_out, int out_size, void* d_ws, size_t ws_size,
                              hipStream_t stream) {
  const float* x = (const float*)d_in[0];   // [32,256,64,64] f32
  const float* cb = (const float*)d_in[1];  // [1024,256] f32
  float* outf = (float*)d_out;              // f32 outputs
  unsigned char* img = (unsigned char*)d_out + IMG_BYTE;
  u64* cand4 = (u64*)((unsigned char*)d_out + CAND_BYTE);
  float* enrm = (float*)((unsigned char*)d_out + ENRM_BYTE);
  (void)in_sizes; (void)n_in; (void)out_size; (void)d_ws; (void)ws_size;

  vq_r7_k0<<<512, 256, 0, stream>>>(cb, img, outf);
  vq_r7_k0b<<<4, 256, 0, stream>>>(cb, enrm);
  vq_r7_k1<<<512, 256, 0, stream>>>(x, img, cand4);
  vq_r7_k2<<<512, 256, 0, stream>>>(x, cb, cand4, enrm, outf);
  vq_r7_k4<<<1, 64, 0, stream>>>(outf);
  vq_r7_k3<<<4096, 256, 0, stream>>>(cb, outf);
}

// Round 9
// 256.510 us; speedup vs baseline: 1.5992x; 1.0118x over previous
//
#include <hip/hip_runtime.h>

// VectorQuantizer on MI355X (gfx950). Round 8: latency fixes — vectorized
// batched A-staging in K1, split f64 chains in K2. Structure otherwise r7.
// d_out (f32): [z_q 33554432][idx 131072][loss 1]  (out_size 33685505)
// Scratch inside z_q's byte region (overwritten by K3 at the end):
//   bytes [67108864, 67633152)  bf16 codebook image in MFMA-fragment order
//   bytes [68157440, 69206016)  cand4: u64[131072] packed top-4 codes
//   bytes [69206016, 69210112)  enrm: f32[1024] exact np-pairwise codebook norms
// Loss slot outf[33685504] = accumulator (K0 zeroes, K2 adds, K4 rescales).

typedef __attribute__((ext_vector_type(8))) short short8;
typedef __attribute__((ext_vector_type(4))) float f32x4;
typedef __attribute__((ext_vector_type(4))) unsigned int u32x4;
typedef unsigned long long u64;

#define IDX_OFF   33554432u
#define LOSS_OFF  33685504u
#define IMG_BYTE  67108864u
#define CAND_BYTE 68157440u
#define ENRM_BYTE 69206016u

__device__ __forceinline__ unsigned short f2bf(float f) {
  unsigned u = __float_as_uint(f);
  unsigned r = (u + 0x7FFFu + ((u >> 16) & 1u)) >> 16;  // RNE
  return (unsigned short)r;
}

// numpy pairwise combine of 8 accumulators
#define COMB(r) __fadd_rn(__fadd_rn(__fadd_rn(r[0], r[1]), __fadd_rn(r[2], r[3])), \
                          __fadd_rn(__fadd_rn(r[4], r[5]), __fadd_rn(r[6], r[7])))

// ---------------- K0: codebook image in MFMA-fragment order + zero loss -------
// img: 16B at ((kc*4+n)*8+ks)*1024 + lane*16 holds code kc*64+n*16+(lane&15),
// d = ks*32 + (lane>>4)*8 + 0..7  (K1 B-frag reads are contiguous 1KB/wave).
extern "C" __global__ __launch_bounds__(256) void vq_r8_k0(const float* __restrict__ cb,
                                                           unsigned char* __restrict__ img,
                                                           float* __restrict__ outf) {
  unsigned tid = blockIdx.x * 256u + threadIdx.x;  // 131072 = (code, dpair)
  unsigned code = tid >> 7, dp = tid & 127u;
  const float* p = cb + (size_t)code * 256u + dp * 2u;
  unsigned u = ((unsigned)f2bf(p[1]) << 16) | (unsigned)f2bf(p[0]);
  unsigned kc = code >> 6, n = (code >> 4) & 3, c16 = code & 15;
  unsigned ks = dp >> 4, g = (dp >> 2) & 3, j = dp & 3;
  unsigned byte = kc * 32768u + (n * 8u + ks) * 1024u + (g * 16u + c16) * 16u + j * 4u;
  *(unsigned*)(img + byte) = u;
  if (tid == 0) outf[LOSS_OFF] = 0.0f;
}

// ---------------- K0b: exact np-f32 pairwise codebook norms -------------------
extern "C" __global__ __launch_bounds__(256) void vq_r8_k0b(const float* __restrict__ cb,
                                                            float* __restrict__ enrm) {
#pragma clang fp contract(off)
  int c = blockIdx.x * 256 + threadIdx.x;  // 4 blocks -> 1024 codes
  const float* e = cb + (size_t)c * 256u;
  float h[2];
#pragma unroll
  for (int half = 0; half < 2; ++half) {
    float r[8];
#pragma unroll
    for (int j = 0; j < 8; ++j) {
      float v = e[half * 128 + j];
      r[j] = __fmul_rn(v, v);
    }
    for (int i = 8; i < 128; i += 8) {
#pragma unroll
      for (int j = 0; j < 8; ++j) {
        float v = e[half * 128 + i + j];
        r[j] = __fadd_rn(r[j], __fmul_rn(v, v));
      }
    }
    h[half] = COMB(r);
  }
  enrm[c] = __fadd_rn(h[0], h[1]);
}

// ---------------- K1: A-in-regs (m=4) MFMA GEMM, conflict-free B --------------
// 256 thr (4 waves), block = 256 pts x 1024 codes, 512 blocks. Wave owns 64 pts.
// B: 16 chunks x 64 codes, fragment-order, double-buffered, 1 barrier/chunk.
extern "C" __global__ __launch_bounds__(256, 2) void vq_r8_k1(const float* __restrict__ x,
                                                              const unsigned char* __restrict__ img,
                                                              u64* __restrict__ cand4) {
  __shared__ __attribute__((aligned(16))) char lds[65536];
  const int t = threadIdx.x;
  const int bid = blockIdx.x;  // 512 blocks
  const int lane = t & 63;
  const int w = t >> 6;
  const int g = lane >> 4, c16 = lane & 15;

  const size_t xbase = (size_t)(bid >> 4) * 1048576u + (size_t)(bid & 15) * 256u;

  // ---- A: two halves of 128 pts staged via LDS transpose, frags to regs ----
  // Vectorized staging: per super-iter a thread loads 2 float4 (4 pts x 2 d),
  // packs 4 u32, writes 4 swizzled LDS words. 32 loads/thread, 8 in flight.
  short8 a[4][8];
  for (int h = 0; h < 2; ++h) {
#pragma unroll 4
    for (int s = 0; s < 16; ++s) {
      int flat = s * 256 + t;   // [0, 4096): 32 pt-groups x 128 dpairs
      int pt4 = flat & 31;
      int dp = flat >> 5;
      const float* px = x + xbase + (size_t)(2 * dp) * 4096u + (unsigned)(h * 128 + pt4 * 4);
      float4 fa = *(const float4*)px;           // d = 2*dp,   pts pt4*4..+3
      float4 fb = *(const float4*)(px + 4096);  // d = 2*dp+1, pts pt4*4..+3
      const float* fap = (const float*)&fa;
      const float* fbp = (const float*)&fb;
#pragma unroll
      for (int k = 0; k < 4; ++k) {
        unsigned u = ((unsigned)f2bf(fbp[k]) << 16) | (unsigned)f2bf(fap[k]);
        int r = pt4 * 4 + k;
        *(unsigned*)(lds + r * 512 + ((dp * 4) ^ ((r & 31) << 2))) = u;
      }
    }
    __syncthreads();
    if ((w >> 1) == h) {
      const int rbase = (w & 1) * 64;
#pragma unroll
      for (int m = 0; m < 4; ++m) {
        const int r = rbase + m * 16 + c16;
        const int rsw = (r & 31) << 2;
#pragma unroll
        for (int ks = 0; ks < 8; ++ks) {
          union { unsigned q[4]; short8 s; } uu;
#pragma unroll
          for (int jj = 0; jj < 4; ++jj)
            uu.q[jj] = *(const unsigned*)(lds + r * 512 + (((ks * 16 + g * 4 + jj) * 4) ^ rsw));
          a[m][ks] = uu.s;
        }
      }
    }
    __syncthreads();
  }

  // ---- B chunk loop: fragment-order flat copy, double-buffered ----
  char* buf0 = lds;
  char* buf1 = lds + 32768;
  u32x4 st[8];
#pragma unroll
  for (int i = 0; i < 8; ++i)
    st[i] = *(const u32x4*)(img + (size_t)((i * 256 + t) * 16));
#pragma unroll
  for (int i = 0; i < 8; ++i)
    *(u32x4*)(buf0 + (i * 256 + t) * 16) = st[i];
  __syncthreads();

  float t1[16], t2[16];
#pragma unroll
  for (int s = 0; s < 16; ++s) { t1[s] = -__builtin_inff(); t2[s] = -__builtin_inff(); }

  int cur = 0;
  for (int kc = 0; kc < 16; ++kc) {
    if (kc < 15) {
      const unsigned char* src = img + (size_t)(kc + 1) * 32768u;
#pragma unroll
      for (int i = 0; i < 8; ++i)
        st[i] = *(const u32x4*)(src + (size_t)((i * 256 + t) * 16));
    }
    const char* B = cur ? buf1 : buf0;
#pragma unroll
    for (int n = 0; n < 4; ++n) {
      f32x4 acc0 = (f32x4){0.f, 0.f, 0.f, 0.f};
      f32x4 acc1 = (f32x4){0.f, 0.f, 0.f, 0.f};
      f32x4 acc2 = (f32x4){0.f, 0.f, 0.f, 0.f};
      f32x4 acc3 = (f32x4){0.f, 0.f, 0.f, 0.f};
#pragma unroll
      for (int ks = 0; ks < 8; ++ks) {
        short8 b = *(const short8*)(B + (n * 8 + ks) * 1024 + lane * 16);  // 1KB/wave contiguous
        acc0 = __builtin_amdgcn_mfma_f32_16x16x32_bf16(a[0][ks], b, acc0, 0, 0, 0);
        acc1 = __builtin_amdgcn_mfma_f32_16x16x32_bf16(a[1][ks], b, acc1, 0, 0, 0);
        acc2 = __builtin_amdgcn_mfma_f32_16x16x32_bf16(a[2][ks], b, acc2, 0, 0, 0);
        acc3 = __builtin_amdgcn_mfma_f32_16x16x32_bf16(a[3][ks], b, acc3, 0, 0, 0);
      }
      const unsigned code = (unsigned)(kc * 64 + n * 16 + c16);
#define SCRN(v, s) { float kf = __uint_as_float((__float_as_uint(v) & 0xFFFFFC00u) | code); \
                     t2[s] = __builtin_amdgcn_fmed3f(kf, t1[s], t2[s]); \
                     t1[s] = fmaxf(t1[s], kf); }
#pragma unroll
      for (int i = 0; i < 4; ++i) {
        SCRN(acc0[i], i);
        SCRN(acc1[i], 4 + i);
        SCRN(acc2[i], 8 + i);
        SCRN(acc3[i], 12 + i);
      }
#undef SCRN
    }
    if (kc < 15) {
      char* Bn = cur ? buf0 : buf1;
#pragma unroll
      for (int i = 0; i < 8; ++i)
        *(u32x4*)(Bn + (i * 256 + t) * 16) = st[i];
    }
    __syncthreads();
    cur ^= 1;
  }

  // ---- merge: kk[pt][class][2] (16 classes = c16), then top-4 of 32 ----
  float* kk = (float*)lds;  // 256 pts x 32 floats = 32KB
#pragma unroll
  for (int m = 0; m < 4; ++m)
#pragma unroll
    for (int i = 0; i < 4; ++i) {
      int pt = w * 64 + m * 16 + g * 4 + i;
      kk[pt * 32 + c16 * 2] = t1[m * 4 + i];
      kk[pt * 32 + c16 * 2 + 1] = t2[m * 4 + i];
    }
  __syncthreads();

  {
    float f1 = -__builtin_inff(), f2v = f1, f3 = f1, f4 = f1;
#pragma unroll
    for (int j = 0; j < 32; ++j) {
      float v = kk[t * 32 + ((j + t) & 31)];
      float b1 = fminf(f1, v);   f1 = fmaxf(f1, v);
      float b2 = fminf(f2v, b1); f2v = fmaxf(f2v, b1);
      float b3 = fminf(f3, b2);  f3 = fmaxf(f3, b2);
      f4 = fmaxf(f4, b3);
    }
    u64 pk = (u64)(__float_as_uint(f1) & 1023u)
           | ((u64)(__float_as_uint(f2v) & 1023u) << 16)
           | ((u64)(__float_as_uint(f3) & 1023u) << 32)
           | ((u64)(__float_as_uint(f4) & 1023u) << 48);
    cand4[(size_t)bid * 256u + (unsigned)t] = pk;
  }
}

// ---------------- K2: exact np-f32 rescore (split f64 chains) -----------------
extern "C" __global__ __launch_bounds__(256) void vq_r8_k2(const float* __restrict__ x,
                                                           const float* __restrict__ cb,
                                                           const u64* __restrict__ cand4,
                                                           const float* __restrict__ enrm,
                                                           float* __restrict__ outf) {
#pragma clang fp contract(off)
  __shared__ float red[4];
  const int t = threadIdx.x;
  const unsigned p = blockIdx.x * 256u + (unsigned)t;

  const u64 pk = cand4[p];
  const int c0 = (int)(pk & 1023u);
  const int c1 = (int)((pk >> 16) & 1023u);
  const int c2 = (int)((pk >> 32) & 1023u);
  const int c3 = (int)((pk >> 48) & 1023u);

  const size_t xoff = ((size_t)(p >> 12)) * 1048576u + (size_t)(p & 4095u);
  const float* e0 = cb + (size_t)c0 * 256u;
  const float* e1 = cb + (size_t)c1 * 256u;
  const float* e2 = cb + (size_t)c2 * 256u;
  const float* e3 = cb + (size_t)c3 * 256u;

  // 2 accumulators per candidate (f64 order-free; only final f32 rounding matters)
  double d0a = 0.0, d0b = 0.0, d1a = 0.0, d1b = 0.0;
  double d2a = 0.0, d2b = 0.0, d3a = 0.0, d3b = 0.0;
  float hs1[2];
#pragma unroll
  for (int half = 0; half < 2; ++half) {
    float r[8];
#pragma unroll
    for (int j = 0; j < 8; ++j) {  // numpy pairwise: accumulators seeded with a[0..7]
      const int d = half * 128 + j;
      const float xv = x[xoff + (size_t)d * 4096u];
      r[j] = __fmul_rn(xv, xv);
      if (j & 1) {
        d0b = fma((double)xv, (double)e0[d], d0b);
        d1b = fma((double)xv, (double)e1[d], d1b);
        d2b = fma((double)xv, (double)e2[d], d2b);
        d3b = fma((double)xv, (double)e3[d], d3b);
      } else {
        d0a = fma((double)xv, (double)e0[d], d0a);
        d1a = fma((double)xv, (double)e1[d], d1a);
        d2a = fma((double)xv, (double)e2[d], d2a);
        d3a = fma((double)xv, (double)e3[d], d3a);
      }
    }
    for (int i = 8; i < 128; i += 8) {
#pragma unroll
      for (int j = 0; j < 8; ++j) {
        const int d = half * 128 + i + j;
        const float xv = x[xoff + (size_t)d * 4096u];
        r[j] = __fadd_rn(r[j], __fmul_rn(xv, xv));
        if (j & 1) {
          d0b = fma((double)xv, (double)e0[d], d0b);
          d1b = fma((double)xv, (double)e1[d], d1b);
          d2b = fma((double)xv, (double)e2[d], d2b);
          d3b = fma((double)xv, (double)e3[d], d3b);
        } else {
          d0a = fma((double)xv, (double)e0[d], d0a);
          d1a = fma((double)xv, (double)e1[d], d1a);
          d2a = fma((double)xv, (double)e2[d], d2a);
          d3a = fma((double)xv, (double)e3[d], d3a);
        }
      }
    }
    hs1[half] = COMB(r);
  }
  const double dt0 = d0a + d0b, dt1 = d1a + d1b, dt2 = d2a + d2b, dt3 = d3a + d3b;
  const float s1v = __fadd_rn(hs1[0], hs1[1]);
  const float s20 = enrm[c0];
  const float s21 = enrm[c1];
  const float s22 = enrm[c2];
  const float s23 = enrm[c3];

  float bestd = __builtin_inff();
  int besti = 0x7FFFFFFF;
  { float dd = __fsub_rn(__fadd_rn(s1v, s20), __fmul_rn(2.0f, (float)dt0));
    if (dd < bestd || (dd == bestd && c0 < besti)) { bestd = dd; besti = c0; } }
  { float dd = __fsub_rn(__fadd_rn(s1v, s21), __fmul_rn(2.0f, (float)dt1));
    if (dd < bestd || (dd == bestd && c1 < besti)) { bestd = dd; besti = c1; } }
  { float dd = __fsub_rn(__fadd_rn(s1v, s22), __fmul_rn(2.0f, (float)dt2));
    if (dd < bestd || (dd == bestd && c2 < besti)) { bestd = dd; besti = c2; } }
  { float dd = __fsub_rn(__fadd_rn(s1v, s23), __fmul_rn(2.0f, (float)dt3));
    if (dd < bestd || (dd == bestd && c3 < besti)) { bestd = dd; besti = c3; } }

  outf[IDX_OFF + p] = (float)besti;  // exact integer in f32

  float sum = bestd;  // loss partial: sum_c (x-q)^2 == s1 + s2 - 2*dot = bestd
#pragma unroll
  for (int off = 32; off > 0; off >>= 1) sum += __shfl_down(sum, off);
  if ((t & 63) == 0) red[t >> 6] = sum;
  __syncthreads();
  if (t == 0) atomicAdd(outf + LOSS_OFF, red[0] + red[1] + red[2] + red[3]);
}

// ---------------- K4: finalize loss in place -----------------------------------
extern "C" __global__ void vq_r8_k4(float* __restrict__ outf) {
  if (threadIdx.x == 0 && blockIdx.x == 0)
    outf[LOSS_OFF] = 2.0f * (outf[LOSS_OFF] / 33554432.0f);
}

// ---------------- K3: z_q via LDS-staged codebook rows, coalesced writes -------
extern "C" __global__ __launch_bounds__(256) void vq_r8_k3(const float* __restrict__ cb,
                                                           float* __restrict__ outf) {
  __shared__ float rows[32 * 257];  // +1-pad: conflict-free column re-read
  const int t = threadIdx.x;
  const unsigned p0 = blockIdx.x * 32u;  // 4096 blocks x 32 points
  const unsigned b = p0 >> 12, hw0 = p0 & 4095u;
  const float* idxf = outf + IDX_OFF;
  for (int i = 0; i < 32; ++i) {
    int row = ((int)idxf[p0 + (unsigned)i]) & 1023;  // broadcast load
    rows[i * 257 + t] = cb[(size_t)row * 256u + (unsigned)t];
  }
  __syncthreads();
  const int j = t & 31, chh = t >> 5;
  float* obase = outf + (size_t)b * 1048576u + hw0 + (unsigned)j;
#pragma unroll
  for (int cc = 0; cc < 32; ++cc) {
    int c = chh * 32 + cc;
    obase[(size_t)c * 4096u] = rows[j * 257 + c];
  }
}

// ---------------- host ---------------------------------------------------------
extern "C" void kernel_launch(void* const* d_in, const int* in_sizes, int n_in,
                              void* d_out, int out_size, void* d_ws, size_t ws_size,
                              hipStream_t stream) {
  const float* x = (const float*)d_in[0];   // [32,256,64,64] f32
  const float* cb = (const float*)d_in[1];  // [1024,256] f32
  float* outf = (float*)d_out;              // f32 outputs
  unsigned char* img = (unsigned char*)d_out + IMG_BYTE;
  u64* cand4 = (u64*)((unsigned char*)d_out + CAND_BYTE);
  float* enrm = (float*)((unsigned char*)d_out + ENRM_BYTE);
  (void)in_sizes; (void)n_in; (void)out_size; (void)d_ws; (void)ws_size;

  vq_r8_k0<<<512, 256, 0, stream>>>(cb, img, outf);
  vq_r8_k0b<<<4, 256, 0, stream>>>(cb, enrm);
  vq_r8_k1<<<512, 256, 0, stream>>>(x, img, cand4);
  vq_r8_k2<<<512, 256, 0, stream>>>(x, cb, cand4, enrm, outf);
  vq_r8_k4<<<1, 64, 0, stream>>>(outf);
  vq_r8_k3<<<4096, 256, 0, stream>>>(cb, outf);
}

// Round 10
// 243.342 us; speedup vs baseline: 1.6857x; 1.0541x over previous
//
#include <hip/hip_runtime.h>

// VectorQuantizer on MI355X (gfx950). Round 9: barrier-free K1 main loop —
// B-frags loaded direct global->reg from the L2-hot fragment-order image
// (no LDS round-trip, no per-chunk __syncthreads). A staged in 32KB quarters.
// K2: float4 candidate-row loads (f64 math bit-identical to r8).
// d_out (f32): [z_q 33554432][idx 131072][loss 1]  (out_size 33685505)
// Scratch inside z_q's byte region (overwritten by K3 at the end):
//   bytes [67108864, 67633152)  bf16 codebook image in MFMA-fragment order
//   bytes [68157440, 69206016)  cand4: u64[131072] packed top-4 codes
//   bytes [69206016, 69210112)  enrm: f32[1024] exact np-pairwise codebook norms
// Loss slot outf[33685504] = accumulator (K0 zeroes, K2 adds, K4 rescales).

typedef __attribute__((ext_vector_type(8))) short short8;
typedef __attribute__((ext_vector_type(4))) float f32x4;
typedef unsigned long long u64;

#define IDX_OFF   33554432u
#define LOSS_OFF  33685504u
#define IMG_BYTE  67108864u
#define CAND_BYTE 68157440u
#define ENRM_BYTE 69206016u

__device__ __forceinline__ unsigned short f2bf(float f) {
  unsigned u = __float_as_uint(f);
  unsigned r = (u + 0x7FFFu + ((u >> 16) & 1u)) >> 16;  // RNE
  return (unsigned short)r;
}

// numpy pairwise combine of 8 accumulators
#define COMB(r) __fadd_rn(__fadd_rn(__fadd_rn(r[0], r[1]), __fadd_rn(r[2], r[3])), \
                          __fadd_rn(__fadd_rn(r[4], r[5]), __fadd_rn(r[6], r[7])))

// ---------------- K0: codebook image in MFMA-fragment order + zero loss -------
// img: 16B at ((kc*4+n)*8+ks)*1024 + lane*16 holds code kc*64+n*16+(lane&15),
// d = ks*32 + (lane>>4)*8 + 0..7  (K1 B-frag loads are contiguous 1KB/wave).
extern "C" __global__ __launch_bounds__(256) void vq_r9_k0(const float* __restrict__ cb,
                                                           unsigned char* __restrict__ img,
                                                           float* __restrict__ outf) {
  unsigned tid = blockIdx.x * 256u + threadIdx.x;  // 131072 = (code, dpair)
  unsigned code = tid >> 7, dp = tid & 127u;
  const float* p = cb + (size_t)code * 256u + dp * 2u;
  unsigned u = ((unsigned)f2bf(p[1]) << 16) | (unsigned)f2bf(p[0]);
  unsigned kc = code >> 6, n = (code >> 4) & 3, c16 = code & 15;
  unsigned ks = dp >> 4, g = (dp >> 2) & 3, j = dp & 3;
  unsigned byte = kc * 32768u + (n * 8u + ks) * 1024u + (g * 16u + c16) * 16u + j * 4u;
  *(unsigned*)(img + byte) = u;
  if (tid == 0) outf[LOSS_OFF] = 0.0f;
}

// ---------------- K0b: exact np-f32 pairwise codebook norms -------------------
extern "C" __global__ __launch_bounds__(256) void vq_r9_k0b(const float* __restrict__ cb,
                                                            float* __restrict__ enrm) {
#pragma clang fp contract(off)
  int c = blockIdx.x * 256 + threadIdx.x;  // 4 blocks -> 1024 codes
  const float* e = cb + (size_t)c * 256u;
  float h[2];
#pragma unroll
  for (int half = 0; half < 2; ++half) {
    float r[8];
#pragma unroll
    for (int j = 0; j < 8; ++j) {
      float v = e[half * 128 + j];
      r[j] = __fmul_rn(v, v);
    }
    for (int i = 8; i < 128; i += 8) {
#pragma unroll
      for (int j = 0; j < 8; ++j) {
        float v = e[half * 128 + i + j];
        r[j] = __fadd_rn(r[j], __fmul_rn(v, v));
      }
    }
    h[half] = COMB(r);
  }
  enrm[c] = __fadd_rn(h[0], h[1]);
}

// ---------------- K1: A-in-regs MFMA GEMM, B direct global->reg ---------------
// 256 thr (4 waves), block = 256 pts x 1024 codes, 512 blocks. Wave owns 64 pts
// (m=4). Main loop: NO LDS, NO barriers — B frags are global dwordx4 from L2.
extern "C" __global__ __launch_bounds__(256, 2) void vq_r9_k1(const float* __restrict__ x,
                                                              const unsigned char* __restrict__ img,
                                                              u64* __restrict__ cand4) {
  __shared__ __attribute__((aligned(16))) char lds[32768];  // A-quarter stage / kk merge
  const int t = threadIdx.x;
  const int bid = blockIdx.x;  // 512 blocks
  const int lane = t & 63;
  const int w = t >> 6;
  const int g = lane >> 4, c16 = lane & 15;

  const size_t xbase = (size_t)(bid >> 4) * 1048576u + (size_t)(bid & 15) * 256u;

  // ---- A: 4 quarters of 64 pts staged via 32KB LDS transpose, frags to regs --
  short8 a[4][8];
  for (int q = 0; q < 4; ++q) {
#pragma unroll 4
    for (int s = 0; s < 8; ++s) {
      int flat = s * 256 + t;   // [0, 2048): 16 pt-groups x 128 dpairs
      int pt4 = flat & 15;
      int dp = flat >> 4;
      const float* px = x + xbase + (size_t)(2 * dp) * 4096u + (unsigned)(q * 64 + pt4 * 4);
      float4 fa = *(const float4*)px;           // d = 2*dp,   4 pts
      float4 fb = *(const float4*)(px + 4096);  // d = 2*dp+1, 4 pts
      const float* fap = (const float*)&fa;
      const float* fbp = (const float*)&fb;
#pragma unroll
      for (int k = 0; k < 4; ++k) {
        unsigned u = ((unsigned)f2bf(fbp[k]) << 16) | (unsigned)f2bf(fap[k]);
        int r = pt4 * 4 + k;  // local row 0..63
        *(unsigned*)(lds + r * 512 + ((dp * 4) ^ ((r & 31) << 2))) = u;
      }
    }
    __syncthreads();
    if (w == q) {
#pragma unroll
      for (int m = 0; m < 4; ++m) {
        const int r = m * 16 + c16;       // local row
        const int rsw = (r & 31) << 2;
#pragma unroll
        for (int ks = 0; ks < 8; ++ks) {
          union { unsigned q4[4]; short8 s8; } uu;
#pragma unroll
          for (int jj = 0; jj < 4; ++jj)
            uu.q4[jj] = *(const unsigned*)(lds + r * 512 + (((ks * 16 + g * 4 + jj) * 4) ^ rsw));
          a[m][ks] = uu.s8;
        }
      }
    }
    __syncthreads();
  }

  // ---- main loop: B frags direct from global (L2-hot), zero barriers ----
  float t1[16], t2[16];
#pragma unroll
  for (int s = 0; s < 16; ++s) { t1[s] = -__builtin_inff(); t2[s] = -__builtin_inff(); }

  const unsigned char* bp = img + (unsigned)(lane * 16);
  for (int kc = 0; kc < 16; ++kc) {
    const unsigned char* bkc = bp + (unsigned)(kc * 32768);
#pragma unroll
    for (int n = 0; n < 4; ++n) {
      short8 bf[8];
#pragma unroll
      for (int ks = 0; ks < 8; ++ks)
        bf[ks] = *(const short8*)(bkc + (unsigned)((n * 8 + ks) * 1024));  // 1KB/wave coalesced
      f32x4 acc0 = (f32x4){0.f, 0.f, 0.f, 0.f};
      f32x4 acc1 = (f32x4){0.f, 0.f, 0.f, 0.f};
      f32x4 acc2 = (f32x4){0.f, 0.f, 0.f, 0.f};
      f32x4 acc3 = (f32x4){0.f, 0.f, 0.f, 0.f};
#pragma unroll
      for (int ks = 0; ks < 8; ++ks) {
        acc0 = __builtin_amdgcn_mfma_f32_16x16x32_bf16(a[0][ks], bf[ks], acc0, 0, 0, 0);
        acc1 = __builtin_amdgcn_mfma_f32_16x16x32_bf16(a[1][ks], bf[ks], acc1, 0, 0, 0);
        acc2 = __builtin_amdgcn_mfma_f32_16x16x32_bf16(a[2][ks], bf[ks], acc2, 0, 0, 0);
        acc3 = __builtin_amdgcn_mfma_f32_16x16x32_bf16(a[3][ks], bf[ks], acc3, 0, 0, 0);
      }
      const unsigned code = (unsigned)(kc * 64 + n * 16 + c16);
#define SCRN(v, s) { float kf = __uint_as_float((__float_as_uint(v) & 0xFFFFFC00u) | code); \
                     t2[s] = __builtin_amdgcn_fmed3f(kf, t1[s], t2[s]); \
                     t1[s] = fmaxf(t1[s], kf); }
#pragma unroll
      for (int i = 0; i < 4; ++i) {
        SCRN(acc0[i], i);
        SCRN(acc1[i], 4 + i);
        SCRN(acc2[i], 8 + i);
        SCRN(acc3[i], 12 + i);
      }
#undef SCRN
    }
  }

  // ---- merge: kk[pt][class][2] (16 classes = c16), then top-4 of 32 ----
  __syncthreads();  // LDS reuse
  float* kk = (float*)lds;  // 256 pts x 32 floats = 32KB
#pragma unroll
  for (int m = 0; m < 4; ++m)
#pragma unroll
    for (int i = 0; i < 4; ++i) {
      int pt = w * 64 + m * 16 + g * 4 + i;
      kk[pt * 32 + c16 * 2] = t1[m * 4 + i];
      kk[pt * 32 + c16 * 2 + 1] = t2[m * 4 + i];
    }
  __syncthreads();

  {
    float f1 = -__builtin_inff(), f2v = f1, f3 = f1, f4 = f1;
#pragma unroll
    for (int j = 0; j < 32; ++j) {
      float v = kk[t * 32 + ((j + t) & 31)];
      float b1 = fminf(f1, v);   f1 = fmaxf(f1, v);
      float b2 = fminf(f2v, b1); f2v = fmaxf(f2v, b1);
      float b3 = fminf(f3, b2);  f3 = fmaxf(f3, b2);
      f4 = fmaxf(f4, b3);
    }
    u64 pk = (u64)(__float_as_uint(f1) & 1023u)
           | ((u64)(__float_as_uint(f2v) & 1023u) << 16)
           | ((u64)(__float_as_uint(f3) & 1023u) << 32)
           | ((u64)(__float_as_uint(f4) & 1023u) << 48);
    cand4[(size_t)bid * 256u + (unsigned)t] = pk;
  }
}

// ---------------- K2: exact np-f32 rescore (float4 row loads) -----------------
// f64 accumulation order is BIT-IDENTICAL to r8's validated (j&1) split.
extern "C" __global__ __launch_bounds__(256) void vq_r9_k2(const float* __restrict__ x,
                                                           const float* __restrict__ cb,
                                                           const u64* __restrict__ cand4,
                                                           const float* __restrict__ enrm,
                                                           float* __restrict__ outf) {
#pragma clang fp contract(off)
  __shared__ float red[4];
  const int t = threadIdx.x;
  const unsigned p = blockIdx.x * 256u + (unsigned)t;

  const u64 pk = cand4[p];
  const int c0 = (int)(pk & 1023u);
  const int c1 = (int)((pk >> 16) & 1023u);
  const int c2 = (int)((pk >> 32) & 1023u);
  const int c3 = (int)((pk >> 48) & 1023u);

  const size_t xoff = ((size_t)(p >> 12)) * 1048576u + (size_t)(p & 4095u);
  const float* e0 = cb + (size_t)c0 * 256u;
  const float* e1 = cb + (size_t)c1 * 256u;
  const float* e2 = cb + (size_t)c2 * 256u;
  const float* e3 = cb + (size_t)c3 * 256u;

  double d0a = 0.0, d0b = 0.0, d1a = 0.0, d1b = 0.0;
  double d2a = 0.0, d2b = 0.0, d3a = 0.0, d3b = 0.0;
  float hs1[2];
#pragma unroll
  for (int half = 0; half < 2; ++half) {
    float r[8];
#pragma unroll 2
    for (int i = 0; i < 128; i += 8) {
      const int dbase = half * 128 + i;
      float xv[8], q0[8], q1[8], q2[8], q3[8];
      *(float4*)(q0) = *(const float4*)(e0 + dbase);
      *(float4*)(q0 + 4) = *(const float4*)(e0 + dbase + 4);
      *(float4*)(q1) = *(const float4*)(e1 + dbase);
      *(float4*)(q1 + 4) = *(const float4*)(e1 + dbase + 4);
      *(float4*)(q2) = *(const float4*)(e2 + dbase);
      *(float4*)(q2 + 4) = *(const float4*)(e2 + dbase + 4);
      *(float4*)(q3) = *(const float4*)(e3 + dbase);
      *(float4*)(q3 + 4) = *(const float4*)(e3 + dbase + 4);
#pragma unroll
      for (int j = 0; j < 8; ++j) xv[j] = x[xoff + (size_t)(dbase + j) * 4096u];
#pragma unroll
      for (int j = 0; j < 8; ++j) {
        // numpy pairwise x-norm: seed at i==0, accumulate after
        r[j] = (i == 0) ? __fmul_rn(xv[j], xv[j])
                        : __fadd_rn(r[j], __fmul_rn(xv[j], xv[j]));
        if (j & 1) {
          d0b = fma((double)xv[j], (double)q0[j], d0b);
          d1b = fma((double)xv[j], (double)q1[j], d1b);
          d2b = fma((double)xv[j], (double)q2[j], d2b);
          d3b = fma((double)xv[j], (double)q3[j], d3b);
        } else {
          d0a = fma((double)xv[j], (double)q0[j], d0a);
          d1a = fma((double)xv[j], (double)q1[j], d1a);
          d2a = fma((double)xv[j], (double)q2[j], d2a);
          d3a = fma((double)xv[j], (double)q3[j], d3a);
        }
      }
    }
    hs1[half] = COMB(r);
  }
  const double dt0 = d0a + d0b, dt1 = d1a + d1b, dt2 = d2a + d2b, dt3 = d3a + d3b;
  const float s1v = __fadd_rn(hs1[0], hs1[1]);
  const float s20 = enrm[c0];
  const float s21 = enrm[c1];
  const float s22 = enrm[c2];
  const float s23 = enrm[c3];

  float bestd = __builtin_inff();
  int besti = 0x7FFFFFFF;
  { float dd = __fsub_rn(__fadd_rn(s1v, s20), __fmul_rn(2.0f, (float)dt0));
    if (dd < bestd || (dd == bestd && c0 < besti)) { bestd = dd; besti = c0; } }
  { float dd = __fsub_rn(__fadd_rn(s1v, s21), __fmul_rn(2.0f, (float)dt1));
    if (dd < bestd || (dd == bestd && c1 < besti)) { bestd = dd; besti = c1; } }
  { float dd = __fsub_rn(__fadd_rn(s1v, s22), __fmul_rn(2.0f, (float)dt2));
    if (dd < bestd || (dd == bestd && c2 < besti)) { bestd = dd; besti = c2; } }
  { float dd = __fsub_rn(__fadd_rn(s1v, s23), __fmul_rn(2.0f, (float)dt3));
    if (dd < bestd || (dd == bestd && c3 < besti)) { bestd = dd; besti = c3; } }

  outf[IDX_OFF + p] = (float)besti;  // exact integer in f32

  float sum = bestd;  // loss partial: sum_c (x-q)^2 == s1 + s2 - 2*dot = bestd
#pragma unroll
  for (int off = 32; off > 0; off >>= 1) sum += __shfl_down(sum, off);
  if ((t & 63) == 0) red[t >> 6] = sum;
  __syncthreads();
  if (t == 0) atomicAdd(outf + LOSS_OFF, red[0] + red[1] + red[2] + red[3]);
}

// ---------------- K4: finalize loss in place -----------------------------------
extern "C" __global__ void vq_r9_k4(float* __restrict__ outf) {
  if (threadIdx.x == 0 && blockIdx.x == 0)
    outf[LOSS_OFF] = 2.0f * (outf[LOSS_OFF] / 33554432.0f);
}

// ---------------- K3: z_q via LDS-staged codebook rows, coalesced writes -------
extern "C" __global__ __launch_bounds__(256) void vq_r9_k3(const float* __restrict__ cb,
                                                           float* __restrict__ outf) {
  __shared__ float rows[32 * 257];  // +1-pad: conflict-free column re-read
  const int t = threadIdx.x;
  const unsigned p0 = blockIdx.x * 32u;  // 4096 blocks x 32 points
  const unsigned b = p0 >> 12, hw0 = p0 & 4095u;
  const float* idxf = outf + IDX_OFF;
  for (int i = 0; i < 32; ++i) {
    int row = ((int)idxf[p0 + (unsigned)i]) & 1023;  // broadcast load
    rows[i * 257 + t] = cb[(size_t)row * 256u + (unsigned)t];
  }
  __syncthreads();
  const int j = t & 31, chh = t >> 5;
  float* obase = outf + (size_t)b * 1048576u + hw0 + (unsigned)j;
#pragma unroll
  for (int cc = 0; cc < 32; ++cc) {
    int c = chh * 32 + cc;
    obase[(size_t)c * 4096u] = rows[j * 257 + c];
  }
}

// ---------------- host ---------------------------------------------------------
extern "C" void kernel_launch(void* const* d_in, const int* in_sizes, int n_in,
                              void* d_out, int out_size, void* d_ws, size_t ws_size,
                              hipStream_t stream) {
  const float* x = (const float*)d_in[0];   // [32,256,64,64] f32
  const float* cb = (const float*)d_in[1];  // [1024,256] f32
  float* outf = (float*)d_out;              // f32 outputs
  unsigned char* img = (unsigned char*)d_out + IMG_BYTE;
  u64* cand4 = (u64*)((unsigned char*)d_out + CAND_BYTE);
  float* enrm = (float*)((unsigned char*)d_out + ENRM_BYTE);
  (void)in_sizes; (void)n_in; (void)out_size; (void)d_ws; (void)ws_size;

  vq_r9_k0<<<512, 256, 0, stream>>>(cb, img, outf);
  vq_r9_k0b<<<4, 256, 0, stream>>>(cb, enrm);
  vq_r9_k1<<<512, 256, 0, stream>>>(x, img, cand4);
  vq_r9_k2<<<512, 256, 0, stream>>>(x, cb, cand4, enrm, outf);
  vq_r9_k4<<<1, 64, 0, stream>>>(outf);
  vq_r9_k3<<<4096, 256, 0, stream>>>(cb, outf);
}

// Round 11
// 205.518 us; speedup vs baseline: 1.9960x; 1.1840x over previous
//
#include <hip/hip_runtime.h>

// VectorQuantizer on MI355X (gfx950). Round 10: candidate-parallel K2
// (wave = candidate, 8 waves/SIMD). K1 barrier-free main loop kept from r9.
// d_out (f32): [z_q 33554432][idx 131072][loss 1]  (out_size 33685505)
// Scratch inside z_q's byte region (overwritten by K3 at the end):
//   bytes [67108864, 67633152)  bf16 codebook image in MFMA-fragment order
//   bytes [68157440, 69206016)  cand4: u64[131072] packed top-4 codes
//   bytes [69206016, 69210112)  enrm: f32[1024] exact np-pairwise codebook norms
// Loss slot outf[33685504] = accumulator (K0 zeroes, K2 adds, K4 rescales).

typedef __attribute__((ext_vector_type(8))) short short8;
typedef __attribute__((ext_vector_type(4))) float f32x4;
typedef unsigned long long u64;

#define IDX_OFF   33554432u
#define LOSS_OFF  33685504u
#define IMG_BYTE  67108864u
#define CAND_BYTE 68157440u
#define ENRM_BYTE 69206016u

__device__ __forceinline__ unsigned short f2bf(float f) {
  unsigned u = __float_as_uint(f);
  unsigned r = (u + 0x7FFFu + ((u >> 16) & 1u)) >> 16;  // RNE
  return (unsigned short)r;
}

// numpy pairwise combine of 8 accumulators
#define COMB(r) __fadd_rn(__fadd_rn(__fadd_rn(r[0], r[1]), __fadd_rn(r[2], r[3])), \
                          __fadd_rn(__fadd_rn(r[4], r[5]), __fadd_rn(r[6], r[7])))

// ---------------- K0: codebook image in MFMA-fragment order + zero loss -------
extern "C" __global__ __launch_bounds__(256) void vq_r10_k0(const float* __restrict__ cb,
                                                            unsigned char* __restrict__ img,
                                                            float* __restrict__ outf) {
  unsigned tid = blockIdx.x * 256u + threadIdx.x;  // 131072 = (code, dpair)
  unsigned code = tid >> 7, dp = tid & 127u;
  const float* p = cb + (size_t)code * 256u + dp * 2u;
  unsigned u = ((unsigned)f2bf(p[1]) << 16) | (unsigned)f2bf(p[0]);
  unsigned kc = code >> 6, n = (code >> 4) & 3, c16 = code & 15;
  unsigned ks = dp >> 4, g = (dp >> 2) & 3, j = dp & 3;
  unsigned byte = kc * 32768u + (n * 8u + ks) * 1024u + (g * 16u + c16) * 16u + j * 4u;
  *(unsigned*)(img + byte) = u;
  if (tid == 0) outf[LOSS_OFF] = 0.0f;
}

// ---------------- K0b: exact np-f32 pairwise codebook norms -------------------
extern "C" __global__ __launch_bounds__(256) void vq_r10_k0b(const float* __restrict__ cb,
                                                             float* __restrict__ enrm) {
#pragma clang fp contract(off)
  int c = blockIdx.x * 256 + threadIdx.x;  // 4 blocks -> 1024 codes
  const float* e = cb + (size_t)c * 256u;
  float h[2];
#pragma unroll
  for (int half = 0; half < 2; ++half) {
    float r[8];
#pragma unroll
    for (int j = 0; j < 8; ++j) {
      float v = e[half * 128 + j];
      r[j] = __fmul_rn(v, v);
    }
    for (int i = 8; i < 128; i += 8) {
#pragma unroll
      for (int j = 0; j < 8; ++j) {
        float v = e[half * 128 + i + j];
        r[j] = __fadd_rn(r[j], __fmul_rn(v, v));
      }
    }
    h[half] = COMB(r);
  }
  enrm[c] = __fadd_rn(h[0], h[1]);
}

// ---------------- K1: A-in-regs MFMA GEMM, B direct global->reg (r9) ----------
extern "C" __global__ __launch_bounds__(256, 2) void vq_r10_k1(const float* __restrict__ x,
                                                               const unsigned char* __restrict__ img,
                                                               u64* __restrict__ cand4) {
  __shared__ __attribute__((aligned(16))) char lds[32768];  // A-quarter stage / kk merge
  const int t = threadIdx.x;
  const int bid = blockIdx.x;  // 512 blocks
  const int lane = t & 63;
  const int w = t >> 6;
  const int g = lane >> 4, c16 = lane & 15;

  const size_t xbase = (size_t)(bid >> 4) * 1048576u + (size_t)(bid & 15) * 256u;

  // ---- A: 4 quarters of 64 pts staged via 32KB LDS transpose, frags to regs --
  short8 a[4][8];
  for (int q = 0; q < 4; ++q) {
#pragma unroll 4
    for (int s = 0; s < 8; ++s) {
      int flat = s * 256 + t;   // [0, 2048): 16 pt-groups x 128 dpairs
      int pt4 = flat & 15;
      int dp = flat >> 4;
      const float* px = x + xbase + (size_t)(2 * dp) * 4096u + (unsigned)(q * 64 + pt4 * 4);
      float4 fa = *(const float4*)px;           // d = 2*dp,   4 pts
      float4 fb = *(const float4*)(px + 4096);  // d = 2*dp+1, 4 pts
      const float* fap = (const float*)&fa;
      const float* fbp = (const float*)&fb;
#pragma unroll
      for (int k = 0; k < 4; ++k) {
        unsigned u = ((unsigned)f2bf(fbp[k]) << 16) | (unsigned)f2bf(fap[k]);
        int r = pt4 * 4 + k;  // local row 0..63
        *(unsigned*)(lds + r * 512 + ((dp * 4) ^ ((r & 31) << 2))) = u;
      }
    }
    __syncthreads();
    if (w == q) {
#pragma unroll
      for (int m = 0; m < 4; ++m) {
        const int r = m * 16 + c16;       // local row
        const int rsw = (r & 31) << 2;
#pragma unroll
        for (int ks = 0; ks < 8; ++ks) {
          union { unsigned q4[4]; short8 s8; } uu;
#pragma unroll
          for (int jj = 0; jj < 4; ++jj)
            uu.q4[jj] = *(const unsigned*)(lds + r * 512 + (((ks * 16 + g * 4 + jj) * 4) ^ rsw));
          a[m][ks] = uu.s8;
        }
      }
    }
    __syncthreads();
  }

  // ---- main loop: B frags direct from global (L2-hot), zero barriers ----
  float t1[16], t2[16];
#pragma unroll
  for (int s = 0; s < 16; ++s) { t1[s] = -__builtin_inff(); t2[s] = -__builtin_inff(); }

  const unsigned char* bp = img + (unsigned)(lane * 16);
  for (int kc = 0; kc < 16; ++kc) {
    const unsigned char* bkc = bp + (unsigned)(kc * 32768);
#pragma unroll
    for (int n = 0; n < 4; ++n) {
      short8 bf[8];
#pragma unroll
      for (int ks = 0; ks < 8; ++ks)
        bf[ks] = *(const short8*)(bkc + (unsigned)((n * 8 + ks) * 1024));  // 1KB/wave coalesced
      f32x4 acc0 = (f32x4){0.f, 0.f, 0.f, 0.f};
      f32x4 acc1 = (f32x4){0.f, 0.f, 0.f, 0.f};
      f32x4 acc2 = (f32x4){0.f, 0.f, 0.f, 0.f};
      f32x4 acc3 = (f32x4){0.f, 0.f, 0.f, 0.f};
#pragma unroll
      for (int ks = 0; ks < 8; ++ks) {
        acc0 = __builtin_amdgcn_mfma_f32_16x16x32_bf16(a[0][ks], bf[ks], acc0, 0, 0, 0);
        acc1 = __builtin_amdgcn_mfma_f32_16x16x32_bf16(a[1][ks], bf[ks], acc1, 0, 0, 0);
        acc2 = __builtin_amdgcn_mfma_f32_16x16x32_bf16(a[2][ks], bf[ks], acc2, 0, 0, 0);
        acc3 = __builtin_amdgcn_mfma_f32_16x16x32_bf16(a[3][ks], bf[ks], acc3, 0, 0, 0);
      }
      const unsigned code = (unsigned)(kc * 64 + n * 16 + c16);
#define SCRN(v, s) { float kf = __uint_as_float((__float_as_uint(v) & 0xFFFFFC00u) | code); \
                     t2[s] = __builtin_amdgcn_fmed3f(kf, t1[s], t2[s]); \
                     t1[s] = fmaxf(t1[s], kf); }
#pragma unroll
      for (int i = 0; i < 4; ++i) {
        SCRN(acc0[i], i);
        SCRN(acc1[i], 4 + i);
        SCRN(acc2[i], 8 + i);
        SCRN(acc3[i], 12 + i);
      }
#undef SCRN
    }
  }

  // ---- merge: kk[pt][class][2] (16 classes = c16), then top-4 of 32 ----
  __syncthreads();  // LDS reuse
  float* kk = (float*)lds;  // 256 pts x 32 floats = 32KB
#pragma unroll
  for (int m = 0; m < 4; ++m)
#pragma unroll
    for (int i = 0; i < 4; ++i) {
      int pt = w * 64 + m * 16 + g * 4 + i;
      kk[pt * 32 + c16 * 2] = t1[m * 4 + i];
      kk[pt * 32 + c16 * 2 + 1] = t2[m * 4 + i];
    }
  __syncthreads();

  {
    float f1 = -__builtin_inff(), f2v = f1, f3 = f1, f4 = f1;
#pragma unroll
    for (int j = 0; j < 32; ++j) {
      float v = kk[t * 32 + ((j + t) & 31)];
      float b1 = fminf(f1, v);   f1 = fmaxf(f1, v);
      float b2 = fminf(f2v, b1); f2v = fmaxf(f2v, b1);
      float b3 = fminf(f3, b2);  f3 = fmaxf(f3, b2);
      f4 = fmaxf(f4, b3);
    }
    u64 pk = (u64)(__float_as_uint(f1) & 1023u)
           | ((u64)(__float_as_uint(f2v) & 1023u) << 16)
           | ((u64)(__float_as_uint(f3) & 1023u) << 32)
           | ((u64)(__float_as_uint(f4) & 1023u) << 48);
    cand4[(size_t)bid * 256u + (unsigned)t] = pk;
  }
}

// ---------------- K2: candidate-parallel exact np-f32 rescore -----------------
// Block = 64 points x 4 candidates (wave = candidate, lane = point). 2048 blocks.
// f64 dot order BIT-IDENTICAL to r9's validated (j&1) split; select in packed
// candidate order with the same tie-break -> idx provably unchanged.
extern "C" __global__ __launch_bounds__(256) void vq_r10_k2(const float* __restrict__ x,
                                                            const float* __restrict__ cb,
                                                            const u64* __restrict__ cand4,
                                                            const float* __restrict__ enrm,
                                                            float* __restrict__ outf) {
#pragma clang fp contract(off)
  __shared__ double dts[4][64];
  __shared__ float s1s[64];
  const int t = threadIdx.x;
  const int pl = t & 63;   // point within block
  const int c = t >> 6;    // candidate index = wave
  const unsigned p = blockIdx.x * 64u + (unsigned)pl;

  const u64 pk = cand4[p];
  const int code = (int)((pk >> (16 * c)) & 1023u);

  const size_t xoff = ((size_t)(p >> 12)) * 1048576u + (size_t)(p & 4095u);
  const float* e = cb + (size_t)code * 256u;

  double da = 0.0, db = 0.0;
  float hs1[2];
#pragma unroll
  for (int half = 0; half < 2; ++half) {
    float r[8];
#pragma unroll 2
    for (int i = 0; i < 128; i += 8) {
      const int dbase = half * 128 + i;
      float q[8], xv[8];
      *(float4*)(q) = *(const float4*)(e + dbase);
      *(float4*)(q + 4) = *(const float4*)(e + dbase + 4);
#pragma unroll
      for (int j = 0; j < 8; ++j) xv[j] = x[xoff + (size_t)(dbase + j) * 4096u];
#pragma unroll
      for (int j = 0; j < 8; ++j) {
        r[j] = (i == 0) ? __fmul_rn(xv[j], xv[j])
                        : __fadd_rn(r[j], __fmul_rn(xv[j], xv[j]));
        if (j & 1) db = fma((double)xv[j], (double)q[j], db);
        else       da = fma((double)xv[j], (double)q[j], da);
      }
    }
    hs1[half] = COMB(r);
  }
  dts[c][pl] = da + db;
  if (c == 0) s1s[pl] = __fadd_rn(hs1[0], hs1[1]);
  __syncthreads();

  if (t < 64) {  // wave 0 selects, packed candidate order, original tie-break
    const float s1v = s1s[pl];
    float bestd = __builtin_inff();
    int besti = 0x7FFFFFFF;
#pragma unroll
    for (int cc = 0; cc < 4; ++cc) {
      const int ccode = (int)((pk >> (16 * cc)) & 1023u);
      float dd = __fsub_rn(__fadd_rn(s1v, enrm[ccode]),
                           __fmul_rn(2.0f, (float)dts[cc][pl]));
      if (dd < bestd || (dd == bestd && ccode < besti)) { bestd = dd; besti = ccode; }
    }
    outf[IDX_OFF + p] = (float)besti;  // exact integer in f32

    float sum = bestd;  // loss partial: sum_c (x-q)^2 == s1 + s2 - 2*dot
#pragma unroll
    for (int off = 32; off > 0; off >>= 1) sum += __shfl_down(sum, off);
    if (pl == 0) atomicAdd(outf + LOSS_OFF, sum);
  }
}

// ---------------- K4: finalize loss in place -----------------------------------
extern "C" __global__ void vq_r10_k4(float* __restrict__ outf) {
  if (threadIdx.x == 0 && blockIdx.x == 0)
    outf[LOSS_OFF] = 2.0f * (outf[LOSS_OFF] / 33554432.0f);
}

// ---------------- K3: z_q via LDS-staged codebook rows, coalesced writes -------
extern "C" __global__ __launch_bounds__(256) void vq_r10_k3(const float* __restrict__ cb,
                                                            float* __restrict__ outf) {
  __shared__ float rows[32 * 257];  // +1-pad: conflict-free column re-read
  const int t = threadIdx.x;
  const unsigned p0 = blockIdx.x * 32u;  // 4096 blocks x 32 points
  const unsigned b = p0 >> 12, hw0 = p0 & 4095u;
  const float* idxf = outf + IDX_OFF;
  for (int i = 0; i < 32; ++i) {
    int row = ((int)idxf[p0 + (unsigned)i]) & 1023;  // broadcast load
    rows[i * 257 + t] = cb[(size_t)row * 256u + (unsigned)t];
  }
  __syncthreads();
  const int j = t & 31, chh = t >> 5;
  float* obase = outf + (size_t)b * 1048576u + hw0 + (unsigned)j;
#pragma unroll
  for (int cc = 0; cc < 32; ++cc) {
    int c = chh * 32 + cc;
    obase[(size_t)c * 4096u] = rows[j * 257 + c];
  }
}

// ---------------- host ---------------------------------------------------------
extern "C" void kernel_launch(void* const* d_in, const int* in_sizes, int n_in,
                              void* d_out, int out_size, void* d_ws, size_t ws_size,
                              hipStream_t stream) {
  const float* x = (const float*)d_in[0];   // [32,256,64,64] f32
  const float* cb = (const float*)d_in[1];  // [1024,256] f32
  float* outf = (float*)d_out;              // f32 outputs
  unsigned char* img = (unsigned char*)d_out + IMG_BYTE;
  u64* cand4 = (u64*)((unsigned char*)d_out + CAND_BYTE);
  float* enrm = (float*)((unsigned char*)d_out + ENRM_BYTE);
  (void)in_sizes; (void)n_in; (void)out_size; (void)d_ws; (void)ws_size;

  vq_r10_k0<<<512, 256, 0, stream>>>(cb, img, outf);
  vq_r10_k0b<<<4, 256, 0, stream>>>(cb, enrm);
  vq_r10_k1<<<512, 256, 0, stream>>>(x, img, cand4);
  vq_r10_k2<<<2048, 256, 0, stream>>>(x, cb, cand4, enrm, outf);
  vq_r10_k4<<<1, 64, 0, stream>>>(outf);
  vq_r10_k3<<<4096, 256, 0, stream>>>(cb, outf);
}